// Round 6
// baseline (2435.346 us; speedup 1.0000x reference)
//
#include <hip/hip_runtime.h>

#define NNODES 60000
#define NPAD   60032
#define NBLK   469      // NPAD/128
#define NEDGES 150000
#define NGRAPH 2048
#define DIM    512
#define NLAYER 5

typedef unsigned short u16;
typedef unsigned int   u32;
typedef _Float16 f16;
typedef __attribute__((ext_vector_type(8))) _Float16 h8;
typedef __attribute__((ext_vector_type(8))) short s16x8;
typedef __attribute__((ext_vector_type(4))) float f32x4;

__device__ __forceinline__ float h2f(u16 u){ return (float)__builtin_bit_cast(f16,u); }
__device__ __forceinline__ u16 f2h(float f){ return __builtin_bit_cast(u16,(f16)f); }

// ---------------- transpose fp32 KxN -> fp16 NxK ----------------
__global__ void transpose_bt(const float* __restrict__ W, u16* __restrict__ Wt, int K, int N){
  __shared__ float tile[32][33];
  int bx=blockIdx.x*32, by=blockIdx.y*32;
  int tx=threadIdx.x&31, ty=threadIdx.x>>5;
  for(int i=ty;i<32;i+=8) tile[i][tx]=W[(size_t)(by+i)*N + bx+tx];
  __syncthreads();
  for(int i=ty;i<32;i+=8) Wt[(size_t)(bx+i)*K + by+tx]=f2h(tile[tx][i]);
}

// ---------------- dense K=40 -> 512, relu, fp16 out ----------------
__global__ void dense40(const float* __restrict__ X, const float* __restrict__ W,
                        const float* __restrict__ b, u16* __restrict__ Y, int M, int Mpad){
  __shared__ float xs[64];
  int t=threadIdx.x;
  int c0=2*t;
  float w0[40], w1[40];
  #pragma unroll
  for(int k=0;k<40;++k){ w0[k]=W[k*DIM+c0]; w1[k]=W[k*DIM+c0+1]; }
  float bb0=b[c0], bb1=b[c0+1];
  for(int m=blockIdx.x;m<Mpad;m+=gridDim.x){
    size_t o=(size_t)m*DIM+c0;
    if(m<M){
      if(t<40) xs[t]=X[m*40+t];
      __syncthreads();
      float a0=bb0, a1=bb1;
      #pragma unroll
      for(int k=0;k<40;++k){ float xv=xs[k]; a0+=xv*w0[k]; a1+=xv*w1[k]; }
      a0=fmaxf(a0,0.f); a1=fmaxf(a1,0.f);
      *(u32*)&Y[o]=(u32)f2h(a0)|((u32)f2h(a1)<<16);
      __syncthreads();
    } else {
      *(u32*)&Y[o]=0u;
    }
  }
}

// ---------------- CSR build ----------------
__global__ void hist_kernel(const int* __restrict__ idx, int* __restrict__ cnt, int n){
  int i=blockIdx.x*256+threadIdx.x;
  if(i<n) atomicAdd(&cnt[idx[i]],1);
}

__global__ void block_sums(const int* __restrict__ in, int* __restrict__ psum, int n){
  __shared__ int s[256];
  int i=blockIdx.x*256+threadIdx.x;
  s[threadIdx.x]=(i<n)?in[i]:0;
  __syncthreads();
  for(int o=128;o;o>>=1){ if(threadIdx.x<o) s[threadIdx.x]+=s[threadIdx.x+o]; __syncthreads(); }
  if(threadIdx.x==0) psum[blockIdx.x]=s[0];
}
__global__ void scan_partials(int* __restrict__ psum, int nb){
  __shared__ int s[256];
  int t=threadIdx.x;
  s[t]=(t<nb)?psum[t]:0;
  __syncthreads();
  for(int o=1;o<256;o<<=1){
    int v=(t>=o)?s[t-o]:0;
    __syncthreads();
    s[t]+=v;
    __syncthreads();
  }
  if(t<nb) psum[t]= t? s[t-1]:0;
}
__global__ void scan_write(const int* __restrict__ in, const int* __restrict__ psum,
                           int* __restrict__ out, int n){
  __shared__ int s[256];
  int t=threadIdx.x;
  int i=blockIdx.x*256+t;
  s[t]=(i<n)?in[i]:0;
  __syncthreads();
  for(int o=1;o<256;o<<=1){
    int v=(t>=o)?s[t-o]:0;
    __syncthreads();
    s[t]+=v;
    __syncthreads();
  }
  if(i<n) out[i+1]=psum[blockIdx.x]+s[t];
  if(i==0) out[0]=0;
}

__global__ void scatter_edges(const int* __restrict__ eidx, const int* __restrict__ eattr,
                              const int* __restrict__ rowptr, int* __restrict__ cnt,
                              u32* __restrict__ es_pk){
  int e=blockIdx.x*256+threadIdx.x;
  if(e>=NEDGES) return;
  int s=eidx[e], d=eidx[NEDGES+e];
  int pos=rowptr[d]+atomicAdd(&cnt[d],1);
  es_pk[pos]=(u32)s | ((u32)(eattr[2*e]*3+eattr[2*e+1])<<16);
}

__global__ void scatter_batch(const int* __restrict__ batch, const int* __restrict__ browptr,
                              int* __restrict__ bcnt, u16* __restrict__ bnodes){
  int n=blockIdx.x*256+threadIdx.x;
  if(n>=NNODES) return;
  int g=batch[n];
  int pos=browptr[g]+atomicAdd(&bcnt[g],1);
  bnodes[pos]=(u16)n;
}

// ---- aggregate with fused BN-affine: x = relu?max(sc*v+sh,0):(sc*v+sh) per column ----
// one WAVE per node row; lane covers 8 cols (16B). combo bank-swizzled.
__global__ void agg_kernel(const u16* __restrict__ src, const float* __restrict__ ss, int relu,
    const int* __restrict__ rowptr, const u32* __restrict__ es_pk,
    const float* __restrict__ emb1, const float* __restrict__ emb2,
    u16* __restrict__ agg, int n0, int n1){
  __shared__ float combo[10*DIM];
  for(int i=threadIdx.x;i<10*DIM;i+=256){
    int c=i>>9, d=i&(DIM-1);
    int bt=(c<9)?(c/3):4, bd=(c<9)?(c%3):0;
    combo[c*DIM + ((d&7)<<6) + (d>>3)] = emb1[bt*DIM+d]+emb2[bd*DIM+d];
  }
  __syncthreads();
  int w=threadIdx.x>>6, l=threadIdx.x&63;
  float sc[8], sh[8];
  #pragma unroll
  for(int j=0;j<8;++j){
    sc[j]= ss? ss[2*DIM + l*8+j] : 1.f;
    sh[j]= ss? ss[3*DIM + l*8+j] : 0.f;
  }
  for(int n=n0+blockIdx.x*4+w; n<n1; n+=gridDim.x*4){
    float a[8];
    if(n<NNODES){
      const float* cb=combo+9*DIM;
      h8 hv=*(const h8*)&src[(size_t)n*DIM + l*8];
      #pragma unroll
      for(int j=0;j<8;++j){
        float x=sc[j]*(float)hv[j]+sh[j];
        if(relu) x=fmaxf(x,0.f);
        a[j]=x+cb[j*64+l];
      }
      int pe=rowptr[n+1];
      for(int p=rowptr[n];p<pe;++p){
        u32 pk=es_pk[p];
        int s=pk&0xFFFF;
        const float* cc=combo+(pk>>16)*DIM;
        h8 sv=*(const h8*)&src[(size_t)s*DIM + l*8];
        #pragma unroll
        for(int j=0;j<8;++j){
          float x=sc[j]*(float)sv[j]+sh[j];
          if(relu) x=fmaxf(x,0.f);
          a[j]+=x+cc[j*64+l];
        }
      }
    } else {
      #pragma unroll
      for(int j=0;j<8;++j) a[j]=0.f;
    }
    s16x8 ov;
    #pragma unroll
    for(int j=0;j<8;++j) ov[j]=(short)f2h(a[j]);
    *(s16x8*)&agg[(size_t)(n-n0)*DIM + l*8]=ov;
  }
}

// ---- fp16 GEMM: C = act(A[MxK]*B[NxK]^T + bias); XCD-swizzled blocks; optional fused BN-stats ----
template<int RELU,int STATS>
__global__ __launch_bounds__(256) void gemm_f16(
    const u16* __restrict__ A, int lda,
    const u16* __restrict__ B, int ldb,
    const float* __restrict__ bias,
    u16* __restrict__ C, int ldc, int K,
    float* __restrict__ stats, int rowlim)
{
  __shared__ u16 As[128*64] __attribute__((aligned(16)));
  __shared__ u16 Bs[128*64] __attribute__((aligned(16)));
  __shared__ float sS[128], sQ[128];
  int t=threadIdx.x, w=t>>6, l=t&63;
  if(STATS){ if(t<128) sS[t]=0.f; else sQ[t-128]=0.f; }
  // T1: bijective XCD-aware remap (consecutive swz ids land on the same XCD)
  int nwg=(int)(gridDim.x*gridDim.y);
  int orig=(int)(blockIdx.y*gridDim.x+blockIdx.x);
  int q=nwg>>3, r=nwg&7, xcd=orig&7, ii=orig>>3;
  int swz=(xcd<r ? xcd*(q+1) : r*(q+1)+(xcd-r)*q) + ii;
  int bx=swz%(int)gridDim.x, by=swz/(int)gridDim.x;
  size_t col0=(size_t)bx*128, row0=(size_t)by*128;
  int wr=w>>1, wc=w&1;
  int lr=l&15, lk=(l>>4)*8;
  f32x4 acc[4][4]={};
  for(int k0=0;k0<K;k0+=64){
    #pragma unroll
    for(int i=0;i<4;++i){
      int c=i*256+t; int rr=c>>3, c8=c&7;
      __builtin_amdgcn_global_load_lds(
        (const __attribute__((address_space(1))) void*)(A+(row0+rr)*lda+k0+c8*8),
        (__attribute__((address_space(3))) void*)(As+(size_t)(i*256+(w<<6))*8), 16,0,0);
      __builtin_amdgcn_global_load_lds(
        (const __attribute__((address_space(1))) void*)(B+(col0+rr)*ldb+k0+c8*8),
        (__attribute__((address_space(3))) void*)(Bs+(size_t)(i*256+(w<<6))*8), 16,0,0);
    }
    __syncthreads();
    #pragma unroll
    for(int kk=0;kk<2;++kk){
      h8 av[4],bv[4];
      #pragma unroll
      for(int m=0;m<4;++m) av[m]=*(const h8*)(As+(wr*64+m*16+lr)*64+kk*32+lk);
      #pragma unroll
      for(int n=0;n<4;++n) bv[n]=*(const h8*)(Bs+(wc*64+n*16+lr)*64+kk*32+lk);
      #pragma unroll
      for(int m=0;m<4;++m)
        #pragma unroll
        for(int n=0;n<4;++n)
          acc[m][n]=__builtin_amdgcn_mfma_f32_16x16x32_f16(av[m],bv[n],acc[m][n],0,0,0);
    }
    __syncthreads();
  }
  #pragma unroll
  for(int n=0;n<4;++n){
    int col=(int)col0+wc*64+n*16+lr;
    float bcol=bias[col];
    float cs=0.f, cq=0.f;
    #pragma unroll
    for(int m=0;m<4;++m){
      int rowb=(int)row0+wr*64+m*16+((l>>4)*4);
      #pragma unroll
      for(int rr=0;rr<4;++rr){
        float v=acc[m][n][rr]+bcol;
        if(RELU) v=fmaxf(v,0.f);
        C[(size_t)(rowb+rr)*ldc+col]=f2h(v);
        if(STATS){ if(rowb+rr<rowlim){ cs+=v; cq+=v*v; } }
      }
    }
    if(STATS){
      cs+=__shfl_xor(cs,16); cs+=__shfl_xor(cs,32);
      cq+=__shfl_xor(cq,16); cq+=__shfl_xor(cq,32);
      if((l>>4)==0){
        atomicAdd(&sS[wc*64+n*16+lr],cs);
        atomicAdd(&sQ[wc*64+n*16+lr],cq);
      }
    }
  }
  if(STATS){
    __syncthreads();
    if(t<128) atomicAdd(&stats[col0+t], sS[t]);
    else      atomicAdd(&stats[DIM+col0+(t-128)], sQ[t-128]);
  }
}

// ---------------- BN finalize: scale/shift from accumulated sum/sumsq ----------------
__global__ void bn_finalize(float* __restrict__ stats, const float* __restrict__ gamma,
                            const float* __restrict__ beta){
  int d=threadIdx.x;
  float mu=stats[d]*(1.f/NNODES);
  float var=stats[DIM+d]*(1.f/NNODES)-mu*mu;
  float sc=gamma[d]*rsqrtf(var+1e-5f);
  stats[2*DIM+d]=sc;
  stats[3*DIM+d]=beta[d]-mu*sc;
}

// ---------------- graph pooling with fused BN-affine (no relu): one wave per graph ----------------
__global__ void batch_reduce(const u16* __restrict__ src, const float* __restrict__ ss,
    const int* __restrict__ browptr, const u16* __restrict__ bnodes, u16* __restrict__ z){
  int w=threadIdx.x>>6, l=threadIdx.x&63;
  int g=blockIdx.x*4+w;
  if(g>=NGRAPH) return;
  float sc[8], sh[8];
  #pragma unroll
  for(int j=0;j<8;++j){ sc[j]=ss[2*DIM+l*8+j]; sh[j]=ss[3*DIM+l*8+j]; }
  float a[8]={0,0,0,0,0,0,0,0};
  int pe=browptr[g+1];
  for(int p=browptr[g];p<pe;++p){
    int n=bnodes[p];
    h8 v=*(const h8*)&src[(size_t)n*DIM + l*8];
    #pragma unroll
    for(int j=0;j<8;++j) a[j]+=sc[j]*(float)v[j]+sh[j];
  }
  s16x8 o;
  #pragma unroll
  for(int j=0;j<8;++j) o[j]=(short)f2h(a[j]);
  *(s16x8*)&z[(size_t)g*1024 + l*8]=o;
}

// ---------------- last layer: dot(128) + bias ----------------
__global__ void last_kernel(const u16* __restrict__ z2, const float* __restrict__ lw,
    const float* __restrict__ lb, float* __restrict__ out){
  int g=blockIdx.x*4+(threadIdx.x>>6), l=threadIdx.x&63;
  float a=h2f(z2[g*128+l])*lw[l]+h2f(z2[g*128+64+l])*lw[64+l];
  #pragma unroll
  for(int off=32;off;off>>=1) a+=__shfl_down(a,off,64);
  if(l==0) out[g]=a+lb[0];
}

extern "C" void kernel_launch(void* const* d_in, const int* in_sizes, int n_in,
                              void* d_out, int out_size, void* d_ws, size_t ws_size,
                              hipStream_t stream){
  (void)in_sizes; (void)n_in; (void)out_size;
  const float* solute_x =(const float*)d_in[0];
  const float* solvent_x=(const float*)d_in[1];
  const int*   eidx     =(const int*)d_in[2];
  const int*   eattr    =(const int*)d_in[3];
  const int*   batch    =(const int*)d_in[4];
  const float* xembW=(const float*)d_in[5];
  const float* xembB=(const float*)d_in[6];
  const float* m1W=(const float*)d_in[7];
  const float* m1b=(const float*)d_in[8];
  const float* m2W=(const float*)d_in[9];
  const float* m2b=(const float*)d_in[10];
  const float* ee1=(const float*)d_in[11];
  const float* ee2=(const float*)d_in[12];
  const float* gam=(const float*)d_in[13];
  const float* bet=(const float*)d_in[14];
  const float* sW1=(const float*)d_in[15];
  const float* sb1=(const float*)d_in[16];
  const float* sW2=(const float*)d_in[17];
  const float* sb2=(const float*)d_in[18];
  const float* oW0=(const float*)d_in[19];
  const float* ob0=(const float*)d_in[20];
  const float* oW1=(const float*)d_in[21];
  const float* ob1=(const float*)d_in[22];
  const float* oW2=(const float*)d_in[23];
  const float* ob2=(const float*)d_in[24];
  const float* lW =(const float*)d_in[25];
  const float* lb =(const float*)d_in[26];
  float* out=(float*)d_out;

  char* p=(char*)d_ws; size_t off=0;
  auto alloc=[&](size_t b)->void*{ void* q=p+off; off+=(b+255)&~(size_t)255; return q; };
  u16* h_f  =(u16*)alloc((size_t)NPAD*DIM*2);
  u16* h2a  =(u16*)alloc((size_t)NPAD*DIM*2);
  u16* h2b  =(u16*)alloc((size_t)NPAD*DIM*2);
  u16* W1t =(u16*)alloc((size_t)NLAYER*1024*512*2);
  u16* W2t =(u16*)alloc((size_t)NLAYER*512*1024*2);
  u16* sW2t=(u16*)alloc((size_t)512*512*2);
  u16* oW0t=(u16*)alloc((size_t)512*1024*2);
  u16* oW1t=(u16*)alloc((size_t)256*512*2);
  u16* oW2t=(u16*)alloc((size_t)128*256*2);
  u16* s1 =(u16*)alloc((size_t)NGRAPH*512*2);
  u16* z  =(u16*)alloc((size_t)NGRAPH*1024*2);
  u16* z0 =(u16*)alloc((size_t)NGRAPH*512*2);
  u16* z1 =(u16*)alloc((size_t)NGRAPH*256*2);
  u16* z2 =(u16*)alloc((size_t)NGRAPH*128*2);
  float* stats=(float*)alloc((size_t)NLAYER*4*DIM*4);   // per-layer sum/sumsq/scale/shift
  int* rowptr =(int*)alloc((size_t)(NNODES+1)*4);
  int* degcnt =(int*)alloc((size_t)NNODES*4);
  u32* es_pk  =(u32*)alloc((size_t)NEDGES*4);
  int* bdeg   =(int*)alloc((size_t)NGRAPH*4);
  int* browptr=(int*)alloc((size_t)(NGRAPH+1)*4);
  int* bcnt   =(int*)alloc((size_t)NGRAPH*4);
  u16* bnodes =(u16*)alloc((size_t)NNODES*2);

  // chunk buffers sized from remaining workspace
  const size_t per_chb=(size_t)128*512*2 + (size_t)128*1024*2;  // agg + t per 128-row block
  size_t left = ws_size>off+4096 ? ws_size-off-4096 : 0;
  int chb=(int)(left/per_chb);
  if(chb<1) return;            // cannot fit: launch nothing (diagnostic)
  if(chb>NBLK) chb=NBLK;
  u16* agg_c=(u16*)alloc((size_t)chb*128*512*2);
  u16* t_c  =(u16*)alloc((size_t)chb*128*1024*2);

  // ---- weight transposes (fp32 -> fp16 NxK) ----
  for(int l=0;l<NLAYER;++l){
    transpose_bt<<<dim3(32,16),256,0,stream>>>(m1W+(size_t)l*512*1024, W1t+(size_t)l*1024*512, 512,1024);
    transpose_bt<<<dim3(16,32),256,0,stream>>>(m2W+(size_t)l*1024*512, W2t+(size_t)l*512*1024, 1024,512);
  }
  transpose_bt<<<dim3(16,16),256,0,stream>>>(sW2, sW2t, 512,512);
  transpose_bt<<<dim3(16,32),256,0,stream>>>(oW0, oW0t, 1024,512);
  transpose_bt<<<dim3(8,16),256,0,stream>>>(oW1, oW1t, 512,256);
  transpose_bt<<<dim3(4,8),256,0,stream>>>(oW2, oW2t, 256,128);

  // ---- embed ----
  dense40<<<2048,256,0,stream>>>(solute_x, xembW, xembB, h_f, NNODES, NPAD);

  // ---- edge CSR (parallel scan) ----
  hipMemsetAsync(degcnt,0,(size_t)NNODES*4,stream);
  hist_kernel<<<(NEDGES+255)/256,256,0,stream>>>(eidx+NEDGES, degcnt, NEDGES);
  {
    int nb=(NNODES+255)/256;   // 235
    block_sums<<<nb,256,0,stream>>>(degcnt, bdeg, NNODES);
    scan_partials<<<1,256,0,stream>>>(bdeg, nb);
    scan_write<<<nb,256,0,stream>>>(degcnt, bdeg, rowptr, NNODES);
  }
  hipMemsetAsync(degcnt,0,(size_t)NNODES*4,stream);
  scatter_edges<<<(NEDGES+255)/256,256,0,stream>>>(eidx, eattr, rowptr, degcnt, es_pk);

  // ---- batch CSR ----
  hipMemsetAsync(bdeg,0,(size_t)NGRAPH*4,stream);
  hist_kernel<<<(NNODES+255)/256,256,0,stream>>>(batch, bdeg, NNODES);
  {
    int nb=(NGRAPH+255)/256;   // 8
    block_sums<<<nb,256,0,stream>>>(bdeg, bcnt, NGRAPH);
    scan_partials<<<1,256,0,stream>>>(bcnt, nb);
    scan_write<<<nb,256,0,stream>>>(bdeg, bcnt, browptr, NGRAPH);
  }
  hipMemsetAsync(bcnt,0,(size_t)NGRAPH*4,stream);
  scatter_batch<<<(NNODES+255)/256,256,0,stream>>>(batch, browptr, bcnt, bnodes);

  // ---- GNN layers (BN fused into agg / batch_reduce; h2 ping-pong to avoid chunk race) ----
  const u16* src=h_f;
  u16* h2buf[2]={h2a,h2b};
  for(int l=0;l<NLAYER;++l){
    const float* e1=ee1+(size_t)l*6*DIM;
    const float* e2=ee2+(size_t)l*3*DIM;
    float* st=stats+(size_t)l*4*DIM;
    const float* ssrc = l? stats+(size_t)(l-1)*4*DIM : nullptr;
    u16* dst=h2buf[l&1];
    hipMemsetAsync(st,0,2*DIM*4,stream);
    for(int b0=0;b0<NBLK;b0+=chb){
      int nb=NBLK-b0; if(nb>chb) nb=chb;
      int n0=b0*128, rows=nb*128;
      agg_kernel<<<2048,256,0,stream>>>(src, ssrc, l?1:0, rowptr, es_pk, e1, e2, agg_c, n0, n0+rows);
      gemm_f16<1,0><<<dim3(8,nb),256,0,stream>>>(agg_c, 512, W1t+(size_t)l*1024*512, 512,
          m1b+(size_t)l*1024, t_c, 1024, 512, nullptr, 1<<30);
      gemm_f16<0,1><<<dim3(4,nb),256,0,stream>>>(t_c, 1024, W2t+(size_t)l*512*1024, 1024,
          m2b+(size_t)l*512, dst+(size_t)n0*DIM, 512, 1024, st, NNODES-n0);
    }
    bn_finalize<<<1,512,0,stream>>>(st, gam+(size_t)l*DIM, bet+(size_t)l*DIM);
    src=dst;
  }

  // ---- pooling + solvent + readout ----
  batch_reduce<<<512,256,0,stream>>>(src, stats+(size_t)(NLAYER-1)*4*DIM, browptr, bnodes, z);
  dense40<<<2048,256,0,stream>>>(solvent_x, sW1, sb1, s1, NGRAPH, NGRAPH);
  gemm_f16<0,0><<<dim3(4,16),256,0,stream>>>(s1, 512, sW2t, 512, sb2, z+512, 1024, 512, nullptr, 1<<30);
  gemm_f16<1,0><<<dim3(4,16),256,0,stream>>>(z, 1024, oW0t, 1024, ob0, z0, 512, 1024, nullptr, 1<<30);
  gemm_f16<1,0><<<dim3(2,16),256,0,stream>>>(z0, 512, oW1t, 512, ob1, z1, 256, 512, nullptr, 1<<30);
  gemm_f16<1,0><<<dim3(1,16),256,0,stream>>>(z1, 256, oW2t, 256, ob2, z2, 128, 256, nullptr, 1<<30);
  last_kernel<<<NGRAPH/4,256,0,stream>>>(z2, lW, lb, out);
}

// Round 7
// 1850.564 us; speedup vs baseline: 1.3160x; 1.3160x over previous
//
#include <hip/hip_runtime.h>

#define NNODES 60000
#define NPAD   60032
#define NBLK   469      // NPAD/128
#define NEDGES 150000
#define NGRAPH 2048
#define DIM    512
#define NLAYER 5

typedef unsigned short u16;
typedef unsigned int   u32;
typedef _Float16 f16;
typedef __attribute__((ext_vector_type(8))) _Float16 h8;
typedef __attribute__((ext_vector_type(8))) short s16x8;
typedef __attribute__((ext_vector_type(4))) float f32x4;

__device__ __forceinline__ float h2f(u16 u){ return (float)__builtin_bit_cast(f16,u); }
__device__ __forceinline__ u16 f2h(float f){ return __builtin_bit_cast(u16,(f16)f); }

// ---------------- transpose fp32 KxN -> fp16 NxK (z = layer) ----------------
__global__ void transpose_bt(const float* __restrict__ W, u16* __restrict__ Wt, int K, int N,
                             size_t strideW, size_t strideWt){
  const float* Wz=W+(size_t)blockIdx.z*strideW;
  u16* Wtz=Wt+(size_t)blockIdx.z*strideWt;
  __shared__ float tile[32][33];
  int bx=blockIdx.x*32, by=blockIdx.y*32;
  int tx=threadIdx.x&31, ty=threadIdx.x>>5;
  for(int i=ty;i<32;i+=8) tile[i][tx]=Wz[(size_t)(by+i)*N + bx+tx];
  __syncthreads();
  for(int i=ty;i<32;i+=8) Wtz[(size_t)(bx+i)*K + by+tx]=f2h(tile[tx][i]);
}

// ---------------- dense K=40 -> 512, relu, fp16 out; 8-row batched ----------------
__global__ __launch_bounds__(256,1) void dense40(
    const float* __restrict__ X, const float* __restrict__ W,
    const float* __restrict__ b, u16* __restrict__ Y, int M, int Mpad){
  __shared__ float xs[8*40];
  int t=threadIdx.x;
  int c0=2*t;
  float w0[40], w1[40];
  #pragma unroll
  for(int k=0;k<40;++k){ w0[k]=W[k*DIM+c0]; w1[k]=W[k*DIM+c0+1]; }
  float bb0=b[c0], bb1=b[c0+1];
  for(int m0=blockIdx.x*8; m0<Mpad; m0+=gridDim.x*8){
    int nr=(m0+8<=M)?8:(M>m0? M-m0:0);
    for(int i=t;i<nr*40;i+=256) xs[i]=X[(size_t)m0*40+i];
    __syncthreads();
    #pragma unroll
    for(int r=0;r<8;++r){
      size_t o=(size_t)(m0+r)*DIM+c0;
      if(r<nr){
        float a0=bb0, a1=bb1;
        const float* xr=xs+r*40;
        #pragma unroll
        for(int k=0;k<40;++k){ float xv=xr[k]; a0+=xv*w0[k]; a1+=xv*w1[k]; }
        a0=fmaxf(a0,0.f); a1=fmaxf(a1,0.f);
        *(u32*)&Y[o]=(u32)f2h(a0)|((u32)f2h(a1)<<16);
      } else {
        *(u32*)&Y[o]=0u;
      }
    }
    __syncthreads();
  }
}

// ---------------- CSR build ----------------
__global__ void hist_kernel(const int* __restrict__ idx, int* __restrict__ cnt, int n){
  int i=blockIdx.x*256+threadIdx.x;
  if(i<n) atomicAdd(&cnt[idx[i]],1);
}

__global__ void block_sums(const int* __restrict__ in, int* __restrict__ psum, int n){
  __shared__ int s[256];
  int i=blockIdx.x*256+threadIdx.x;
  s[threadIdx.x]=(i<n)?in[i]:0;
  __syncthreads();
  for(int o=128;o;o>>=1){ if(threadIdx.x<o) s[threadIdx.x]+=s[threadIdx.x+o]; __syncthreads(); }
  if(threadIdx.x==0) psum[blockIdx.x]=s[0];
}
__global__ void scan_partials(int* __restrict__ psum, int nb){
  __shared__ int s[256];
  int t=threadIdx.x;
  s[t]=(t<nb)?psum[t]:0;
  __syncthreads();
  for(int o=1;o<256;o<<=1){
    int v=(t>=o)?s[t-o]:0;
    __syncthreads();
    s[t]+=v;
    __syncthreads();
  }
  if(t<nb) psum[t]= t? s[t-1]:0;
}
__global__ void scan_write(const int* __restrict__ in, const int* __restrict__ psum,
                           int* __restrict__ out, int n){
  __shared__ int s[256];
  int t=threadIdx.x;
  int i=blockIdx.x*256+t;
  s[t]=(i<n)?in[i]:0;
  __syncthreads();
  for(int o=1;o<256;o<<=1){
    int v=(t>=o)?s[t-o]:0;
    __syncthreads();
    s[t]+=v;
    __syncthreads();
  }
  if(i<n) out[i+1]=psum[blockIdx.x]+s[t];
  if(i==0) out[0]=0;
}

__global__ void scatter_edges(const int* __restrict__ eidx, const int* __restrict__ eattr,
                              const int* __restrict__ rowptr, int* __restrict__ cnt,
                              u32* __restrict__ es_pk){
  int e=blockIdx.x*256+threadIdx.x;
  if(e>=NEDGES) return;
  int s=eidx[e], d=eidx[NEDGES+e];
  int pos=rowptr[d]+atomicAdd(&cnt[d],1);
  es_pk[pos]=(u32)s | ((u32)(eattr[2*e]*3+eattr[2*e+1])<<16);
}

__global__ void scatter_batch(const int* __restrict__ batch, const int* __restrict__ browptr,
                              int* __restrict__ bcnt, u16* __restrict__ bnodes){
  int n=blockIdx.x*256+threadIdx.x;
  if(n>=NNODES) return;
  int g=batch[n];
  int pos=browptr[g]+atomicAdd(&bcnt[g],1);
  bnodes[pos]=(u16)n;
}

// ---- aggregate: one WAVE per node row; lane covers 8 cols (16B). combo bank-swizzled. ----
__global__ void agg_kernel(const u16* __restrict__ h, const int* __restrict__ rowptr,
    const u32* __restrict__ es_pk, const float* __restrict__ emb1, const float* __restrict__ emb2,
    u16* __restrict__ agg, int n0, int n1){
  __shared__ float combo[10*DIM];
  for(int i=threadIdx.x;i<10*DIM;i+=256){
    int c=i>>9, d=i&(DIM-1);
    int bt=(c<9)?(c/3):4, bd=(c<9)?(c%3):0;
    combo[c*DIM + ((d&7)<<6) + (d>>3)] = emb1[bt*DIM+d]+emb2[bd*DIM+d];
  }
  __syncthreads();
  int w=threadIdx.x>>6, l=threadIdx.x&63;
  for(int n=n0+blockIdx.x*4+w; n<n1; n+=gridDim.x*4){
    float a[8];
    if(n<NNODES){
      const float* cb=combo+9*DIM;
      h8 hv=*(const h8*)&h[(size_t)n*DIM + l*8];
      #pragma unroll
      for(int j=0;j<8;++j) a[j]=(float)hv[j]+cb[j*64+l];
      int pe=rowptr[n+1];
      for(int p=rowptr[n];p<pe;++p){
        u32 pk=es_pk[p];
        int s=pk&0xFFFF;
        const float* cc=combo+(pk>>16)*DIM;
        h8 sv=*(const h8*)&h[(size_t)s*DIM + l*8];
        #pragma unroll
        for(int j=0;j<8;++j) a[j]+=(float)sv[j]+cc[j*64+l];
      }
    } else {
      #pragma unroll
      for(int j=0;j<8;++j) a[j]=0.f;
    }
    s16x8 ov;
    #pragma unroll
    for(int j=0;j<8;++j) ov[j]=(short)f2h(a[j]);
    *(s16x8*)&agg[(size_t)(n-n0)*DIM + l*8]=ov;
  }
}

// ---- fp16 GEMM: C = act(A[MxK]*B[NxK]^T + bias); XCD-swizzled blocks; optional fused BN-stats ----
template<int RELU,int STATS>
__global__ __launch_bounds__(256) void gemm_f16(
    const u16* __restrict__ A, int lda,
    const u16* __restrict__ B, int ldb,
    const float* __restrict__ bias,
    u16* __restrict__ C, int ldc, int K,
    float* __restrict__ stats, int rowlim)
{
  __shared__ u16 As[128*64] __attribute__((aligned(16)));
  __shared__ u16 Bs[128*64] __attribute__((aligned(16)));
  __shared__ float sS[128], sQ[128];
  int t=threadIdx.x, w=t>>6, l=t&63;
  if(STATS){ if(t<128) sS[t]=0.f; else sQ[t-128]=0.f; }
  // T1: bijective XCD-aware remap (consecutive swz ids land on the same XCD)
  int nwg=(int)(gridDim.x*gridDim.y);
  int orig=(int)(blockIdx.y*gridDim.x+blockIdx.x);
  int q=nwg>>3, r=nwg&7, xcd=orig&7, ii=orig>>3;
  int swz=(xcd<r ? xcd*(q+1) : r*(q+1)+(xcd-r)*q) + ii;
  int bx=swz%(int)gridDim.x, by=swz/(int)gridDim.x;
  size_t col0=(size_t)bx*128, row0=(size_t)by*128;
  int wr=w>>1, wc=w&1;
  int lr=l&15, lk=(l>>4)*8;
  f32x4 acc[4][4]={};
  for(int k0=0;k0<K;k0+=64){
    #pragma unroll
    for(int i=0;i<4;++i){
      int c=i*256+t; int rr=c>>3, c8=c&7;
      __builtin_amdgcn_global_load_lds(
        (const __attribute__((address_space(1))) void*)(A+(row0+rr)*lda+k0+c8*8),
        (__attribute__((address_space(3))) void*)(As+(size_t)(i*256+(w<<6))*8), 16,0,0);
      __builtin_amdgcn_global_load_lds(
        (const __attribute__((address_space(1))) void*)(B+(col0+rr)*ldb+k0+c8*8),
        (__attribute__((address_space(3))) void*)(Bs+(size_t)(i*256+(w<<6))*8), 16,0,0);
    }
    __syncthreads();
    #pragma unroll
    for(int kk=0;kk<2;++kk){
      h8 av[4],bv[4];
      #pragma unroll
      for(int m=0;m<4;++m) av[m]=*(const h8*)(As+(wr*64+m*16+lr)*64+kk*32+lk);
      #pragma unroll
      for(int n=0;n<4;++n) bv[n]=*(const h8*)(Bs+(wc*64+n*16+lr)*64+kk*32+lk);
      #pragma unroll
      for(int m=0;m<4;++m)
        #pragma unroll
        for(int n=0;n<4;++n)
          acc[m][n]=__builtin_amdgcn_mfma_f32_16x16x32_f16(av[m],bv[n],acc[m][n],0,0,0);
    }
    __syncthreads();
  }
  #pragma unroll
  for(int n=0;n<4;++n){
    int col=(int)col0+wc*64+n*16+lr;
    float bcol=bias[col];
    float cs=0.f, cq=0.f;
    #pragma unroll
    for(int m=0;m<4;++m){
      int rowb=(int)row0+wr*64+m*16+((l>>4)*4);
      #pragma unroll
      for(int rr=0;rr<4;++rr){
        float v=acc[m][n][rr]+bcol;
        if(RELU) v=fmaxf(v,0.f);
        C[(size_t)(rowb+rr)*ldc+col]=f2h(v);
        if(STATS){ if(rowb+rr<rowlim){ cs+=v; cq+=v*v; } }
      }
    }
    if(STATS){
      cs+=__shfl_xor(cs,16); cs+=__shfl_xor(cs,32);
      cq+=__shfl_xor(cq,16); cq+=__shfl_xor(cq,32);
      if((l>>4)==0){
        atomicAdd(&sS[wc*64+n*16+lr],cs);
        atomicAdd(&sQ[wc*64+n*16+lr],cq);
      }
    }
  }
  if(STATS){
    __syncthreads();
    if(t<128) atomicAdd(&stats[col0+t], sS[t]);
    else      atomicAdd(&stats[DIM+col0+(t-128)], sQ[t-128]);
  }
}

// ---------------- BN finalize + apply ----------------
__global__ void bn_finalize(float* __restrict__ stats, const float* __restrict__ gamma,
                            const float* __restrict__ beta){
  int d=threadIdx.x;
  float mu=stats[d]*(1.f/NNODES);
  float var=stats[DIM+d]*(1.f/NNODES)-mu*mu;
  float sc=gamma[d]*rsqrtf(var+1e-5f);
  stats[2*DIM+d]=sc;
  stats[3*DIM+d]=beta[d]-mu*sc;
}

__global__ void bn_apply(const u16* __restrict__ h2, const float* __restrict__ stats,
    u16* __restrict__ h, int relu){
  int idx=blockIdx.x*256+threadIdx.x;  // NNODES*64 threads, 8 elems each
  int d0=(idx&63)*8;
  size_t base=(size_t)idx*8;
  h8 v=*(const h8*)&h2[base];
  s16x8 o;
  #pragma unroll
  for(int j=0;j<8;++j){
    int d=d0+j;
    float x=(float)v[j]*stats[2*DIM+d]+stats[3*DIM+d];
    if(relu) x=fmaxf(x,0.f);
    o[j]=(short)f2h(x);
  }
  *(s16x8*)&h[base]=o;
}

// ---------------- graph pooling: one wave per graph ----------------
__global__ void batch_reduce(const u16* __restrict__ h, const int* __restrict__ browptr,
    const u16* __restrict__ bnodes, u16* __restrict__ z){
  int w=threadIdx.x>>6, l=threadIdx.x&63;
  int g=blockIdx.x*4+w;
  if(g>=NGRAPH) return;
  float a[8]={0,0,0,0,0,0,0,0};
  int pe=browptr[g+1];
  for(int p=browptr[g];p<pe;++p){
    int n=bnodes[p];
    h8 v=*(const h8*)&h[(size_t)n*DIM + l*8];
    #pragma unroll
    for(int j=0;j<8;++j) a[j]+=(float)v[j];
  }
  s16x8 o;
  #pragma unroll
  for(int j=0;j<8;++j) o[j]=(short)f2h(a[j]);
  *(s16x8*)&z[(size_t)g*1024 + l*8]=o;
}

// ---------------- last layer: dot(128) + bias ----------------
__global__ void last_kernel(const u16* __restrict__ z2, const float* __restrict__ lw,
    const float* __restrict__ lb, float* __restrict__ out){
  int g=blockIdx.x*4+(threadIdx.x>>6), l=threadIdx.x&63;
  float a=h2f(z2[g*128+l])*lw[l]+h2f(z2[g*128+64+l])*lw[64+l];
  #pragma unroll
  for(int off=32;off;off>>=1) a+=__shfl_down(a,off,64);
  if(l==0) out[g]=a+lb[0];
}

extern "C" void kernel_launch(void* const* d_in, const int* in_sizes, int n_in,
                              void* d_out, int out_size, void* d_ws, size_t ws_size,
                              hipStream_t stream){
  (void)in_sizes; (void)n_in; (void)out_size;
  const float* solute_x =(const float*)d_in[0];
  const float* solvent_x=(const float*)d_in[1];
  const int*   eidx     =(const int*)d_in[2];
  const int*   eattr    =(const int*)d_in[3];
  const int*   batch    =(const int*)d_in[4];
  const float* xembW=(const float*)d_in[5];
  const float* xembB=(const float*)d_in[6];
  const float* m1W=(const float*)d_in[7];
  const float* m1b=(const float*)d_in[8];
  const float* m2W=(const float*)d_in[9];
  const float* m2b=(const float*)d_in[10];
  const float* ee1=(const float*)d_in[11];
  const float* ee2=(const float*)d_in[12];
  const float* gam=(const float*)d_in[13];
  const float* bet=(const float*)d_in[14];
  const float* sW1=(const float*)d_in[15];
  const float* sb1=(const float*)d_in[16];
  const float* sW2=(const float*)d_in[17];
  const float* sb2=(const float*)d_in[18];
  const float* oW0=(const float*)d_in[19];
  const float* ob0=(const float*)d_in[20];
  const float* oW1=(const float*)d_in[21];
  const float* ob1=(const float*)d_in[22];
  const float* oW2=(const float*)d_in[23];
  const float* ob2=(const float*)d_in[24];
  const float* lW =(const float*)d_in[25];
  const float* lb =(const float*)d_in[26];
  float* out=(float*)d_out;

  char* p=(char*)d_ws; size_t off=0;
  auto alloc=[&](size_t b)->void*{ void* q=p+off; off+=(b+255)&~(size_t)255; return q; };
  u16* h_f   =(u16*)alloc((size_t)NPAD*DIM*2);
  u16* h2_f  =(u16*)alloc((size_t)NPAD*DIM*2);
  u16* W1t =(u16*)alloc((size_t)NLAYER*1024*512*2);
  u16* W2t =(u16*)alloc((size_t)NLAYER*512*1024*2);
  u16* sW2t=(u16*)alloc((size_t)512*512*2);
  u16* oW0t=(u16*)alloc((size_t)512*1024*2);
  u16* oW1t=(u16*)alloc((size_t)256*512*2);
  u16* oW2t=(u16*)alloc((size_t)128*256*2);
  u16* s1 =(u16*)alloc((size_t)NGRAPH*512*2);
  u16* z  =(u16*)alloc((size_t)NGRAPH*1024*2);
  u16* z0 =(u16*)alloc((size_t)NGRAPH*512*2);
  u16* z1 =(u16*)alloc((size_t)NGRAPH*256*2);
  u16* z2 =(u16*)alloc((size_t)NGRAPH*128*2);
  float* stats=(float*)alloc(4*DIM*4);
  int* rowptr =(int*)alloc((size_t)(NNODES+1)*4);
  int* degcnt =(int*)alloc((size_t)NNODES*4);
  u32* es_pk  =(u32*)alloc((size_t)NEDGES*4);
  int* bdeg   =(int*)alloc((size_t)NGRAPH*4);
  int* browptr=(int*)alloc((size_t)(NGRAPH+1)*4);
  int* bcnt   =(int*)alloc((size_t)NGRAPH*4);
  u16* bnodes =(u16*)alloc((size_t)NNODES*2);

  // chunk buffers sized from remaining workspace
  const size_t per_chb=(size_t)128*512*2 + (size_t)128*1024*2;  // agg + t per 128-row block
  size_t left = ws_size>off+4096 ? ws_size-off-4096 : 0;
  int chb=(int)(left/per_chb);
  if(chb<1) return;            // cannot fit: launch nothing (diagnostic)
  if(chb>NBLK) chb=NBLK;
  u16* agg_c=(u16*)alloc((size_t)chb*128*512*2);
  u16* t_c  =(u16*)alloc((size_t)chb*128*1024*2);

  // ---- weight transposes (fp32 -> fp16 NxK); layer dim in z ----
  transpose_bt<<<dim3(32,16,NLAYER),256,0,stream>>>(m1W, W1t, 512,1024, (size_t)512*1024, (size_t)1024*512);
  transpose_bt<<<dim3(16,32,NLAYER),256,0,stream>>>(m2W, W2t, 1024,512, (size_t)1024*512, (size_t)512*1024);
  transpose_bt<<<dim3(16,16,1),256,0,stream>>>(sW2, sW2t, 512,512, 0,0);
  transpose_bt<<<dim3(16,32,1),256,0,stream>>>(oW0, oW0t, 1024,512, 0,0);
  transpose_bt<<<dim3(8,16,1),256,0,stream>>>(oW1, oW1t, 512,256, 0,0);
  transpose_bt<<<dim3(4,8,1),256,0,stream>>>(oW2, oW2t, 256,128, 0,0);

  // ---- embed ----
  dense40<<<1024,256,0,stream>>>(solute_x, xembW, xembB, h_f, NNODES, NPAD);

  // ---- edge CSR (parallel scan) ----
  hipMemsetAsync(degcnt,0,(size_t)NNODES*4,stream);
  hist_kernel<<<(NEDGES+255)/256,256,0,stream>>>(eidx+NEDGES, degcnt, NEDGES);
  {
    int nb=(NNODES+255)/256;   // 235
    block_sums<<<nb,256,0,stream>>>(degcnt, bdeg, NNODES);
    scan_partials<<<1,256,0,stream>>>(bdeg, nb);
    scan_write<<<nb,256,0,stream>>>(degcnt, bdeg, rowptr, NNODES);
  }
  hipMemsetAsync(degcnt,0,(size_t)NNODES*4,stream);
  scatter_edges<<<(NEDGES+255)/256,256,0,stream>>>(eidx, eattr, rowptr, degcnt, es_pk);

  // ---- batch CSR ----
  hipMemsetAsync(bdeg,0,(size_t)NGRAPH*4,stream);
  hist_kernel<<<(NNODES+255)/256,256,0,stream>>>(batch, bdeg, NNODES);
  {
    int nb=(NGRAPH+255)/256;   // 8
    block_sums<<<nb,256,0,stream>>>(bdeg, bcnt, NGRAPH);
    scan_partials<<<1,256,0,stream>>>(bcnt, nb);
    scan_write<<<nb,256,0,stream>>>(bdeg, bcnt, browptr, NGRAPH);
  }
  hipMemsetAsync(bcnt,0,(size_t)NGRAPH*4,stream);
  scatter_batch<<<(NNODES+255)/256,256,0,stream>>>(batch, browptr, bcnt, bnodes);

  // ---- GNN layers (r5 dataflow: lean agg -> gemm1 -> gemm2(stats) -> finalize -> bn_apply) ----
  for(int l=0;l<NLAYER;++l){
    const float* e1=ee1+(size_t)l*6*DIM;
    const float* e2=ee2+(size_t)l*3*DIM;
    hipMemsetAsync(stats,0,2*DIM*4,stream);
    for(int b0=0;b0<NBLK;b0+=chb){
      int nb=NBLK-b0; if(nb>chb) nb=chb;
      int n0=b0*128, rows=nb*128;
      agg_kernel<<<2048,256,0,stream>>>(h_f, rowptr, es_pk, e1, e2, agg_c, n0, n0+rows);
      gemm_f16<1,0><<<dim3(8,nb),256,0,stream>>>(agg_c, 512, W1t+(size_t)l*1024*512, 512,
          m1b+(size_t)l*1024, t_c, 1024, 512, nullptr, 1<<30);
      gemm_f16<0,1><<<dim3(4,nb),256,0,stream>>>(t_c, 1024, W2t+(size_t)l*512*1024, 1024,
          m2b+(size_t)l*512, h2_f+(size_t)n0*DIM, 512, 1024, stats, NNODES-n0);
    }
    bn_finalize<<<1,512,0,stream>>>(stats, gam+(size_t)l*DIM, bet+(size_t)l*DIM);
    bn_apply<<<(NNODES*64)/256,256,0,stream>>>(h2_f, stats, h_f, (l<NLAYER-1)?1:0);
  }

  // ---- pooling + solvent + readout ----
  batch_reduce<<<512,256,0,stream>>>(h_f, browptr, bnodes, z);
  dense40<<<1024,256,0,stream>>>(solvent_x, sW1, sb1, s1, NGRAPH, NGRAPH);
  gemm_f16<0,0><<<dim3(4,16),256,0,stream>>>(s1, 512, sW2t, 512, sb2, z+512, 1024, 512, nullptr, 1<<30);
  gemm_f16<1,0><<<dim3(4,16),256,0,stream>>>(z, 1024, oW0t, 1024, ob0, z0, 512, 1024, nullptr, 1<<30);
  gemm_f16<1,0><<<dim3(2,16),256,0,stream>>>(z0, 512, oW1t, 512, ob1, z1, 256, 512, nullptr, 1<<30);
  gemm_f16<1,0><<<dim3(1,16),256,0,stream>>>(z1, 256, oW2t, 256, ob2, z2, 128, 256, nullptr, 1<<30);
  last_kernel<<<NGRAPH/4,256,0,stream>>>(z2, lW, lb, out);
}

// Round 8
// 1814.172 us; speedup vs baseline: 1.3424x; 1.0201x over previous
//
#include <hip/hip_runtime.h>

#define NNODES 60000
#define NPAD   60032
#define NBLK   469      // NPAD/128
#define NEDGES 150000
#define NGRAPH 2048
#define DIM    512
#define NLAYER 5

typedef unsigned short u16;
typedef unsigned int   u32;
typedef _Float16 f16;
typedef __attribute__((ext_vector_type(8))) _Float16 h8;
typedef __attribute__((ext_vector_type(8))) short s16x8;
typedef __attribute__((ext_vector_type(4))) float f32x4;

__device__ __forceinline__ float h2f(u16 u){ return (float)__builtin_bit_cast(f16,u); }
__device__ __forceinline__ u16 f2h(float f){ return __builtin_bit_cast(u16,(f16)f); }

// ---------------- transpose fp32 KxN -> fp16 NxK (z = layer) ----------------
__global__ void transpose_bt(const float* __restrict__ W, u16* __restrict__ Wt, int K, int N,
                             size_t strideW, size_t strideWt){
  const float* Wz=W+(size_t)blockIdx.z*strideW;
  u16* Wtz=Wt+(size_t)blockIdx.z*strideWt;
  __shared__ float tile[32][33];
  int bx=blockIdx.x*32, by=blockIdx.y*32;
  int tx=threadIdx.x&31, ty=threadIdx.x>>5;
  for(int i=ty;i<32;i+=8) tile[i][tx]=Wz[(size_t)(by+i)*N + bx+tx];
  __syncthreads();
  for(int i=ty;i<32;i+=8) Wtz[(size_t)(bx+i)*K + by+tx]=f2h(tile[tx][i]);
}

// ---------------- dense K=40 -> 512, relu, fp16 out; 8-row batched ----------------
__global__ __launch_bounds__(256,1) void dense40(
    const float* __restrict__ X, const float* __restrict__ W,
    const float* __restrict__ b, u16* __restrict__ Y, int M, int Mpad){
  __shared__ float xs[8*40];
  int t=threadIdx.x;
  int c0=2*t;
  float w0[40], w1[40];
  #pragma unroll
  for(int k=0;k<40;++k){ w0[k]=W[k*DIM+c0]; w1[k]=W[k*DIM+c0+1]; }
  float bb0=b[c0], bb1=b[c0+1];
  for(int m0=blockIdx.x*8; m0<Mpad; m0+=gridDim.x*8){
    int nr=(m0+8<=M)?8:(M>m0? M-m0:0);
    for(int i=t;i<nr*40;i+=256) xs[i]=X[(size_t)m0*40+i];
    __syncthreads();
    #pragma unroll
    for(int r=0;r<8;++r){
      size_t o=(size_t)(m0+r)*DIM+c0;
      if(r<nr){
        float a0=bb0, a1=bb1;
        const float* xr=xs+r*40;
        #pragma unroll
        for(int k=0;k<40;++k){ float xv=xr[k]; a0+=xv*w0[k]; a1+=xv*w1[k]; }
        a0=fmaxf(a0,0.f); a1=fmaxf(a1,0.f);
        *(u32*)&Y[o]=(u32)f2h(a0)|((u32)f2h(a1)<<16);
      } else {
        *(u32*)&Y[o]=0u;
      }
    }
    __syncthreads();
  }
}

// ---------------- CSR build ----------------
__global__ void hist_kernel(const int* __restrict__ idx, int* __restrict__ cnt, int n){
  int i=blockIdx.x*256+threadIdx.x;
  if(i<n) atomicAdd(&cnt[idx[i]],1);
}

__global__ void block_sums(const int* __restrict__ in, int* __restrict__ psum, int n){
  __shared__ int s[256];
  int i=blockIdx.x*256+threadIdx.x;
  s[threadIdx.x]=(i<n)?in[i]:0;
  __syncthreads();
  for(int o=128;o;o>>=1){ if(threadIdx.x<o) s[threadIdx.x]+=s[threadIdx.x+o]; __syncthreads(); }
  if(threadIdx.x==0) psum[blockIdx.x]=s[0];
}
__global__ void scan_partials(int* __restrict__ psum, int nb){
  __shared__ int s[256];
  int t=threadIdx.x;
  s[t]=(t<nb)?psum[t]:0;
  __syncthreads();
  for(int o=1;o<256;o<<=1){
    int v=(t>=o)?s[t-o]:0;
    __syncthreads();
    s[t]+=v;
    __syncthreads();
  }
  if(t<nb) psum[t]= t? s[t-1]:0;
}
__global__ void scan_write(const int* __restrict__ in, const int* __restrict__ psum,
                           int* __restrict__ out, int n){
  __shared__ int s[256];
  int t=threadIdx.x;
  int i=blockIdx.x*256+t;
  s[t]=(i<n)?in[i]:0;
  __syncthreads();
  for(int o=1;o<256;o<<=1){
    int v=(t>=o)?s[t-o]:0;
    __syncthreads();
    s[t]+=v;
    __syncthreads();
  }
  if(i<n) out[i+1]=psum[blockIdx.x]+s[t];
  if(i==0) out[0]=0;
}

__global__ void scatter_edges(const int* __restrict__ eidx, const int* __restrict__ eattr,
                              const int* __restrict__ rowptr, int* __restrict__ cnt,
                              u32* __restrict__ es_pk){
  int e=blockIdx.x*256+threadIdx.x;
  if(e>=NEDGES) return;
  int s=eidx[e], d=eidx[NEDGES+e];
  int pos=rowptr[d]+atomicAdd(&cnt[d],1);
  es_pk[pos]=(u32)s | ((u32)(eattr[2*e]*3+eattr[2*e+1])<<16);
}

__global__ void scatter_batch(const int* __restrict__ batch, const int* __restrict__ browptr,
                              int* __restrict__ bcnt, u16* __restrict__ bnodes){
  int n=blockIdx.x*256+threadIdx.x;
  if(n>=NNODES) return;
  int g=batch[n];
  int pos=browptr[g]+atomicAdd(&bcnt[g],1);
  bnodes[pos]=(u16)n;
}

// ---- aggregate: one WAVE per node row; packed fp16 adds; combo fp16 in LDS (1 b128/edge) ----
__global__ void agg_kernel(const u16* __restrict__ h, const int* __restrict__ rowptr,
    const u32* __restrict__ es_pk, const float* __restrict__ emb1, const float* __restrict__ emb2,
    u16* __restrict__ agg, int n0, int n1){
  __shared__ u16 combo[10*DIM];
  for(int i=threadIdx.x;i<10*DIM;i+=256){
    int c=i>>9, d=i&(DIM-1);
    int bt=(c<9)?(c/3):4, bd=(c<9)?(c%3):0;
    combo[c*DIM+d]=f2h(emb1[bt*DIM+d]+emb2[bd*DIM+d]);
  }
  __syncthreads();
  int w=threadIdx.x>>6, l=threadIdx.x&63;
  const h8 cb9=*(const h8*)&combo[9*DIM+l*8];
  for(int n=n0+blockIdx.x*4+w; n<n1; n+=gridDim.x*4){
    h8 a={};
    if(n<NNODES){
      a=*(const h8*)&h[(size_t)n*DIM+l*8] + cb9;
      int pe=rowptr[n+1];
      for(int p=rowptr[n];p<pe;++p){
        u32 pk=es_pk[p];
        h8 sv=*(const h8*)&h[(size_t)(pk&0xFFFFu)*DIM+l*8];
        h8 cc=*(const h8*)&combo[(pk>>16)*DIM+l*8];
        a+=sv+cc;
      }
    }
    *(h8*)&agg[(size_t)(n-n0)*DIM+l*8]=a;
  }
}

// ---- fp16 GEMM: C = act(A[MxK]*B[NxK]^T + bias); XCD-swizzled blocks; optional fused BN-stats ----
template<int RELU,int STATS>
__global__ __launch_bounds__(256) void gemm_f16(
    const u16* __restrict__ A, int lda,
    const u16* __restrict__ B, int ldb,
    const float* __restrict__ bias,
    u16* __restrict__ C, int ldc, int K,
    float* __restrict__ stats, int rowlim)
{
  __shared__ u16 As[128*64] __attribute__((aligned(16)));
  __shared__ u16 Bs[128*64] __attribute__((aligned(16)));
  __shared__ float sS[128], sQ[128];
  int t=threadIdx.x, w=t>>6, l=t&63;
  if(STATS){ if(t<128) sS[t]=0.f; else sQ[t-128]=0.f; }
  // T1: bijective XCD-aware remap
  int nwg=(int)(gridDim.x*gridDim.y);
  int orig=(int)(blockIdx.y*gridDim.x+blockIdx.x);
  int q=nwg>>3, r=nwg&7, xcd=orig&7, ii=orig>>3;
  int swz=(xcd<r ? xcd*(q+1) : r*(q+1)+(xcd-r)*q) + ii;
  int bx=swz%(int)gridDim.x, by=swz/(int)gridDim.x;
  size_t col0=(size_t)bx*128, row0=(size_t)by*128;
  int wr=w>>1, wc=w&1;
  int lr=l&15, lk=(l>>4)*8;
  f32x4 acc[4][4]={};
  for(int k0=0;k0<K;k0+=64){
    #pragma unroll
    for(int i=0;i<4;++i){
      int c=i*256+t; int rr=c>>3, c8=c&7;
      __builtin_amdgcn_global_load_lds(
        (const __attribute__((address_space(1))) void*)(A+(row0+rr)*lda+k0+c8*8),
        (__attribute__((address_space(3))) void*)(As+(size_t)(i*256+(w<<6))*8), 16,0,0);
      __builtin_amdgcn_global_load_lds(
        (const __attribute__((address_space(1))) void*)(B+(col0+rr)*ldb+k0+c8*8),
        (__attribute__((address_space(3))) void*)(Bs+(size_t)(i*256+(w<<6))*8), 16,0,0);
    }
    __syncthreads();
    #pragma unroll
    for(int kk=0;kk<2;++kk){
      h8 av[4],bv[4];
      #pragma unroll
      for(int m=0;m<4;++m) av[m]=*(const h8*)(As+(wr*64+m*16+lr)*64+kk*32+lk);
      #pragma unroll
      for(int n=0;n<4;++n) bv[n]=*(const h8*)(Bs+(wc*64+n*16+lr)*64+kk*32+lk);
      #pragma unroll
      for(int m=0;m<4;++m)
        #pragma unroll
        for(int n=0;n<4;++n)
          acc[m][n]=__builtin_amdgcn_mfma_f32_16x16x32_f16(av[m],bv[n],acc[m][n],0,0,0);
    }
    __syncthreads();
  }
  #pragma unroll
  for(int n=0;n<4;++n){
    int col=(int)col0+wc*64+n*16+lr;
    float bcol=bias[col];
    float cs=0.f, cq=0.f;
    #pragma unroll
    for(int m=0;m<4;++m){
      int rowb=(int)row0+wr*64+m*16+((l>>4)*4);
      #pragma unroll
      for(int rr=0;rr<4;++rr){
        float v=acc[m][n][rr]+bcol;
        if(RELU) v=fmaxf(v,0.f);
        C[(size_t)(rowb+rr)*ldc+col]=f2h(v);
        if(STATS){ if(rowb+rr<rowlim){ cs+=v; cq+=v*v; } }
      }
    }
    if(STATS){
      cs+=__shfl_xor(cs,16); cs+=__shfl_xor(cs,32);
      cq+=__shfl_xor(cq,16); cq+=__shfl_xor(cq,32);
      if((l>>4)==0){
        atomicAdd(&sS[wc*64+n*16+lr],cs);
        atomicAdd(&sQ[wc*64+n*16+lr],cq);
      }
    }
  }
  if(STATS){
    __syncthreads();
    if(t<128) atomicAdd(&stats[col0+t], sS[t]);
    else      atomicAdd(&stats[DIM+col0+(t-128)], sQ[t-128]);
  }
}

// ---------------- BN finalize ----------------
__global__ void bn_finalize(float* __restrict__ stats, const float* __restrict__ gamma,
                            const float* __restrict__ beta){
  int d=threadIdx.x;
  float mu=stats[d]*(1.f/NNODES);
  float var=stats[DIM+d]*(1.f/NNODES)-mu*mu;
  float sc=gamma[d]*rsqrtf(var+1e-5f);
  stats[2*DIM+d]=sc;
  stats[3*DIM+d]=beta[d]-mu*sc;
}

// ---- BN apply + relu: one wave per row, stats in registers, packed fp16 fma ----
__global__ void bn_apply(const u16* __restrict__ h2, const float* __restrict__ stats,
    u16* __restrict__ h){
  int w=threadIdx.x>>6, l=threadIdx.x&63;
  h8 scv, shv;
  #pragma unroll
  for(int j=0;j<8;++j){ scv[j]=(f16)stats[2*DIM+l*8+j]; shv[j]=(f16)stats[3*DIM+l*8+j]; }
  for(int n=blockIdx.x*4+w; n<NNODES; n+=gridDim.x*4){
    size_t o=(size_t)n*DIM+l*8;
    h8 v=*(const h8*)&h2[o];
    h8 x=v*scv+shv;
    s16x8 xi=__builtin_bit_cast(s16x8,x);
    #pragma unroll
    for(int j=0;j<8;++j) xi[j]=(xi[j]<0)?0:xi[j];   // relu via sign bit
    *(s16x8*)&h[o]=xi;
  }
}

// ---- graph pooling with fused BN affine (no relu): one wave per graph ----
__global__ void batch_reduce(const u16* __restrict__ h2, const float* __restrict__ stats,
    const int* __restrict__ browptr, const u16* __restrict__ bnodes, u16* __restrict__ z){
  int w=threadIdx.x>>6, l=threadIdx.x&63;
  int g=blockIdx.x*4+w;
  if(g>=NGRAPH) return;
  float sc[8], sh[8];
  #pragma unroll
  for(int j=0;j<8;++j){ sc[j]=stats[2*DIM+l*8+j]; sh[j]=stats[3*DIM+l*8+j]; }
  float a[8]={0,0,0,0,0,0,0,0};
  int pe=browptr[g+1];
  for(int p=browptr[g];p<pe;++p){
    int n=bnodes[p];
    h8 v=*(const h8*)&h2[(size_t)n*DIM + l*8];
    #pragma unroll
    for(int j=0;j<8;++j) a[j]+=sc[j]*(float)v[j]+sh[j];
  }
  s16x8 o;
  #pragma unroll
  for(int j=0;j<8;++j) o[j]=(short)f2h(a[j]);
  *(s16x8*)&z[(size_t)g*1024 + l*8]=o;
}

// ---------------- last layer: dot(128) + bias ----------------
__global__ void last_kernel(const u16* __restrict__ z2, const float* __restrict__ lw,
    const float* __restrict__ lb, float* __restrict__ out){
  int g=blockIdx.x*4+(threadIdx.x>>6), l=threadIdx.x&63;
  float a=h2f(z2[g*128+l])*lw[l]+h2f(z2[g*128+64+l])*lw[64+l];
  #pragma unroll
  for(int off=32;off;off>>=1) a+=__shfl_down(a,off,64);
  if(l==0) out[g]=a+lb[0];
}

extern "C" void kernel_launch(void* const* d_in, const int* in_sizes, int n_in,
                              void* d_out, int out_size, void* d_ws, size_t ws_size,
                              hipStream_t stream){
  (void)in_sizes; (void)n_in; (void)out_size;
  const float* solute_x =(const float*)d_in[0];
  const float* solvent_x=(const float*)d_in[1];
  const int*   eidx     =(const int*)d_in[2];
  const int*   eattr    =(const int*)d_in[3];
  const int*   batch    =(const int*)d_in[4];
  const float* xembW=(const float*)d_in[5];
  const float* xembB=(const float*)d_in[6];
  const float* m1W=(const float*)d_in[7];
  const float* m1b=(const float*)d_in[8];
  const float* m2W=(const float*)d_in[9];
  const float* m2b=(const float*)d_in[10];
  const float* ee1=(const float*)d_in[11];
  const float* ee2=(const float*)d_in[12];
  const float* gam=(const float*)d_in[13];
  const float* bet=(const float*)d_in[14];
  const float* sW1=(const float*)d_in[15];
  const float* sb1=(const float*)d_in[16];
  const float* sW2=(const float*)d_in[17];
  const float* sb2=(const float*)d_in[18];
  const float* oW0=(const float*)d_in[19];
  const float* ob0=(const float*)d_in[20];
  const float* oW1=(const float*)d_in[21];
  const float* ob1=(const float*)d_in[22];
  const float* oW2=(const float*)d_in[23];
  const float* ob2=(const float*)d_in[24];
  const float* lW =(const float*)d_in[25];
  const float* lb =(const float*)d_in[26];
  float* out=(float*)d_out;

  char* p=(char*)d_ws; size_t off=0;
  auto alloc=[&](size_t b)->void*{ void* q=p+off; off+=(b+255)&~(size_t)255; return q; };
  u16* h_f   =(u16*)alloc((size_t)NPAD*DIM*2);
  u16* h2_f  =(u16*)alloc((size_t)NPAD*DIM*2);
  u16* W1t =(u16*)alloc((size_t)NLAYER*1024*512*2);
  u16* W2t =(u16*)alloc((size_t)NLAYER*512*1024*2);
  u16* sW2t=(u16*)alloc((size_t)512*512*2);
  u16* oW0t=(u16*)alloc((size_t)512*1024*2);
  u16* oW1t=(u16*)alloc((size_t)256*512*2);
  u16* oW2t=(u16*)alloc((size_t)128*256*2);
  u16* s1 =(u16*)alloc((size_t)NGRAPH*512*2);
  u16* z  =(u16*)alloc((size_t)NGRAPH*1024*2);
  u16* z0 =(u16*)alloc((size_t)NGRAPH*512*2);
  u16* z1 =(u16*)alloc((size_t)NGRAPH*256*2);
  u16* z2 =(u16*)alloc((size_t)NGRAPH*128*2);
  float* stats=(float*)alloc(4*DIM*4);
  int* rowptr =(int*)alloc((size_t)(NNODES+1)*4);
  int* degcnt =(int*)alloc((size_t)NNODES*4);
  u32* es_pk  =(u32*)alloc((size_t)NEDGES*4);
  int* bdeg   =(int*)alloc((size_t)NGRAPH*4);
  int* browptr=(int*)alloc((size_t)(NGRAPH+1)*4);
  int* bcnt   =(int*)alloc((size_t)NGRAPH*4);
  u16* bnodes =(u16*)alloc((size_t)NNODES*2);

  const size_t per_chb=(size_t)128*512*2 + (size_t)128*1024*2;
  size_t left = ws_size>off+4096 ? ws_size-off-4096 : 0;
  int chb=(int)(left/per_chb);
  if(chb<1) return;
  if(chb>NBLK) chb=NBLK;
  u16* agg_c=(u16*)alloc((size_t)chb*128*512*2);
  u16* t_c  =(u16*)alloc((size_t)chb*128*1024*2);

  // ---- weight transposes ----
  transpose_bt<<<dim3(32,16,NLAYER),256,0,stream>>>(m1W, W1t, 512,1024, (size_t)512*1024, (size_t)1024*512);
  transpose_bt<<<dim3(16,32,NLAYER),256,0,stream>>>(m2W, W2t, 1024,512, (size_t)1024*512, (size_t)512*1024);
  transpose_bt<<<dim3(16,16,1),256,0,stream>>>(sW2, sW2t, 512,512, 0,0);
  transpose_bt<<<dim3(16,32,1),256,0,stream>>>(oW0, oW0t, 1024,512, 0,0);
  transpose_bt<<<dim3(8,16,1),256,0,stream>>>(oW1, oW1t, 512,256, 0,0);
  transpose_bt<<<dim3(4,8,1),256,0,stream>>>(oW2, oW2t, 256,128, 0,0);

  // ---- embed ----
  dense40<<<1024,256,0,stream>>>(solute_x, xembW, xembB, h_f, NNODES, NPAD);

  // ---- edge CSR ----
  hipMemsetAsync(degcnt,0,(size_t)NNODES*4,stream);
  hist_kernel<<<(NEDGES+255)/256,256,0,stream>>>(eidx+NEDGES, degcnt, NEDGES);
  {
    int nb=(NNODES+255)/256;
    block_sums<<<nb,256,0,stream>>>(degcnt, bdeg, NNODES);
    scan_partials<<<1,256,0,stream>>>(bdeg, nb);
    scan_write<<<nb,256,0,stream>>>(degcnt, bdeg, rowptr, NNODES);
  }
  hipMemsetAsync(degcnt,0,(size_t)NNODES*4,stream);
  scatter_edges<<<(NEDGES+255)/256,256,0,stream>>>(eidx, eattr, rowptr, degcnt, es_pk);

  // ---- batch CSR ----
  hipMemsetAsync(bdeg,0,(size_t)NGRAPH*4,stream);
  hist_kernel<<<(NNODES+255)/256,256,0,stream>>>(batch, bdeg, NNODES);
  {
    int nb=(NGRAPH+255)/256;
    block_sums<<<nb,256,0,stream>>>(bdeg, bcnt, NGRAPH);
    scan_partials<<<1,256,0,stream>>>(bcnt, nb);
    scan_write<<<nb,256,0,stream>>>(bdeg, bcnt, browptr, NGRAPH);
  }
  hipMemsetAsync(bcnt,0,(size_t)NGRAPH*4,stream);
  scatter_batch<<<(NNODES+255)/256,256,0,stream>>>(batch, browptr, bcnt, bnodes);

  // ---- GNN layers ----
  for(int l=0;l<NLAYER;++l){
    const float* e1=ee1+(size_t)l*6*DIM;
    const float* e2=ee2+(size_t)l*3*DIM;
    hipMemsetAsync(stats,0,2*DIM*4,stream);
    for(int b0=0;b0<NBLK;b0+=chb){
      int nb=NBLK-b0; if(nb>chb) nb=chb;
      int n0=b0*128, rows=nb*128;
      agg_kernel<<<2048,256,0,stream>>>(h_f, rowptr, es_pk, e1, e2, agg_c, n0, n0+rows);
      gemm_f16<1,0><<<dim3(8,nb),256,0,stream>>>(agg_c, 512, W1t+(size_t)l*1024*512, 512,
          m1b+(size_t)l*1024, t_c, 1024, 512, nullptr, 1<<30);
      gemm_f16<0,1><<<dim3(4,nb),256,0,stream>>>(t_c, 1024, W2t+(size_t)l*512*1024, 1024,
          m2b+(size_t)l*512, h2_f+(size_t)n0*DIM, 512, 1024, stats, NNODES-n0);
    }
    bn_finalize<<<1,512,0,stream>>>(stats, gam+(size_t)l*DIM, bet+(size_t)l*DIM);
    if(l<NLAYER-1)
      bn_apply<<<2048,256,0,stream>>>(h2_f, stats, h_f);
  }

  // ---- pooling (layer-4 BN affine fused) + solvent + readout ----
  batch_reduce<<<512,256,0,stream>>>(h2_f, stats, browptr, bnodes, z);
  dense40<<<1024,256,0,stream>>>(solvent_x, sW1, sb1, s1, NGRAPH, NGRAPH);
  gemm_f16<0,0><<<dim3(4,16),256,0,stream>>>(s1, 512, sW2t, 512, sb2, z+512, 1024, 512, nullptr, 1<<30);
  gemm_f16<1,0><<<dim3(4,16),256,0,stream>>>(z, 1024, oW0t, 1024, ob0, z0, 512, 1024, nullptr, 1<<30);
  gemm_f16<1,0><<<dim3(2,16),256,0,stream>>>(z0, 512, oW1t, 512, ob1, z1, 256, 512, nullptr, 1<<30);
  gemm_f16<1,0><<<dim3(1,16),256,0,stream>>>(z1, 256, oW2t, 256, ob2, z2, 128, 256, nullptr, 1<<30);
  last_kernel<<<NGRAPH/4,256,0,stream>>>(z2, lW, lb, out);
}

// Round 9
// 1457.198 us; speedup vs baseline: 1.6713x; 1.2450x over previous
//
#include <hip/hip_runtime.h>

#define NNODES 60000
#define NPAD   60032
#define NBLK   469      // NPAD/128
#define NEDGES 150000
#define NGRAPH 2048
#define DIM    512
#define NLAYER 5

typedef unsigned short u16;
typedef unsigned int   u32;
typedef _Float16 f16;
typedef __attribute__((ext_vector_type(8))) _Float16 h8;
typedef __attribute__((ext_vector_type(8))) short s16x8;
typedef __attribute__((ext_vector_type(4))) float f32x4;

__device__ __forceinline__ float h2f(u16 u){ return (float)__builtin_bit_cast(f16,u); }
__device__ __forceinline__ u16 f2h(float f){ return __builtin_bit_cast(u16,(f16)f); }

// ---------------- transpose fp32 KxN -> fp16 NxK (z = layer) ----------------
__global__ void transpose_bt(const float* __restrict__ W, u16* __restrict__ Wt, int K, int N,
                             size_t strideW, size_t strideWt){
  const float* Wz=W+(size_t)blockIdx.z*strideW;
  u16* Wtz=Wt+(size_t)blockIdx.z*strideWt;
  __shared__ float tile[32][33];
  int bx=blockIdx.x*32, by=blockIdx.y*32;
  int tx=threadIdx.x&31, ty=threadIdx.x>>5;
  for(int i=ty;i<32;i+=8) tile[i][tx]=Wz[(size_t)(by+i)*N + bx+tx];
  __syncthreads();
  for(int i=ty;i<32;i+=8) Wtz[(size_t)(bx+i)*K + by+tx]=f2h(tile[tx][i]);
}

// ---------------- dense K=40 -> 512, relu, fp16 out; 8-row batched ----------------
__global__ __launch_bounds__(256,1) void dense40(
    const float* __restrict__ X, const float* __restrict__ W,
    const float* __restrict__ b, u16* __restrict__ Y, int M, int Mpad){
  __shared__ float xs[8*40];
  int t=threadIdx.x;
  int c0=2*t;
  float w0[40], w1[40];
  #pragma unroll
  for(int k=0;k<40;++k){ w0[k]=W[k*DIM+c0]; w1[k]=W[k*DIM+c0+1]; }
  float bb0=b[c0], bb1=b[c0+1];
  for(int m0=blockIdx.x*8; m0<Mpad; m0+=gridDim.x*8){
    int nr=(m0+8<=M)?8:(M>m0? M-m0:0);
    for(int i=t;i<nr*40;i+=256) xs[i]=X[(size_t)m0*40+i];
    __syncthreads();
    #pragma unroll
    for(int r=0;r<8;++r){
      size_t o=(size_t)(m0+r)*DIM+c0;
      if(r<nr){
        float a0=bb0, a1=bb1;
        const float* xr=xs+r*40;
        #pragma unroll
        for(int k=0;k<40;++k){ float xv=xr[k]; a0+=xv*w0[k]; a1+=xv*w1[k]; }
        a0=fmaxf(a0,0.f); a1=fmaxf(a1,0.f);
        *(u32*)&Y[o]=(u32)f2h(a0)|((u32)f2h(a1)<<16);
      } else {
        *(u32*)&Y[o]=0u;
      }
    }
    __syncthreads();
  }
}

// ---------------- CSR build ----------------
__global__ void hist_kernel(const int* __restrict__ idx, int* __restrict__ cnt, int n){
  int i=blockIdx.x*256+threadIdx.x;
  if(i<n) atomicAdd(&cnt[idx[i]],1);
}

__global__ void block_sums(const int* __restrict__ in, int* __restrict__ psum, int n){
  __shared__ int s[256];
  int i=blockIdx.x*256+threadIdx.x;
  s[threadIdx.x]=(i<n)?in[i]:0;
  __syncthreads();
  for(int o=128;o;o>>=1){ if(threadIdx.x<o) s[threadIdx.x]+=s[threadIdx.x+o]; __syncthreads(); }
  if(threadIdx.x==0) psum[blockIdx.x]=s[0];
}
__global__ void scan_partials(int* __restrict__ psum, int nb){
  __shared__ int s[256];
  int t=threadIdx.x;
  s[t]=(t<nb)?psum[t]:0;
  __syncthreads();
  for(int o=1;o<256;o<<=1){
    int v=(t>=o)?s[t-o]:0;
    __syncthreads();
    s[t]+=v;
    __syncthreads();
  }
  if(t<nb) psum[t]= t? s[t-1]:0;
}
__global__ void scan_write(const int* __restrict__ in, const int* __restrict__ psum,
                           int* __restrict__ out, int n){
  __shared__ int s[256];
  int t=threadIdx.x;
  int i=blockIdx.x*256+t;
  s[t]=(i<n)?in[i]:0;
  __syncthreads();
  for(int o=1;o<256;o<<=1){
    int v=(t>=o)?s[t-o]:0;
    __syncthreads();
    s[t]+=v;
    __syncthreads();
  }
  if(i<n) out[i+1]=psum[blockIdx.x]+s[t];
  if(i==0) out[0]=0;
}

__global__ void scatter_edges(const int* __restrict__ eidx, const int* __restrict__ eattr,
                              const int* __restrict__ rowptr, int* __restrict__ cnt,
                              u32* __restrict__ es_pk){
  int e=blockIdx.x*256+threadIdx.x;
  if(e>=NEDGES) return;
  int s=eidx[e], d=eidx[NEDGES+e];
  int pos=rowptr[d]+atomicAdd(&cnt[d],1);
  es_pk[pos]=(u32)s | ((u32)(eattr[2*e]*3+eattr[2*e+1])<<16);
}

__global__ void scatter_batch(const int* __restrict__ batch, const int* __restrict__ browptr,
                              int* __restrict__ bcnt, u16* __restrict__ bnodes){
  int n=blockIdx.x*256+threadIdx.x;
  if(n>=NNODES) return;
  int g=batch[n];
  int pos=browptr[g]+atomicAdd(&bcnt[g],1);
  bnodes[pos]=(u16)n;
}

// ---- aggregate: one WAVE per node row; packed fp16 adds; combo fp16 in LDS (1 b128/edge) ----
__global__ void agg_kernel(const u16* __restrict__ h, const int* __restrict__ rowptr,
    const u32* __restrict__ es_pk, const float* __restrict__ emb1, const float* __restrict__ emb2,
    u16* __restrict__ agg, int n0, int n1){
  __shared__ u16 combo[10*DIM];
  for(int i=threadIdx.x;i<10*DIM;i+=256){
    int c=i>>9, d=i&(DIM-1);
    int bt=(c<9)?(c/3):4, bd=(c<9)?(c%3):0;
    combo[c*DIM+d]=f2h(emb1[bt*DIM+d]+emb2[bd*DIM+d]);
  }
  __syncthreads();
  int w=threadIdx.x>>6, l=threadIdx.x&63;
  const h8 cb9=*(const h8*)&combo[9*DIM+l*8];
  for(int n=n0+blockIdx.x*4+w; n<n1; n+=gridDim.x*4){
    h8 a={};
    if(n<NNODES){
      a=*(const h8*)&h[(size_t)n*DIM+l*8] + cb9;
      int pe=rowptr[n+1];
      for(int p=rowptr[n];p<pe;++p){
        u32 pk=es_pk[p];
        h8 sv=*(const h8*)&h[(size_t)(pk&0xFFFFu)*DIM+l*8];
        h8 cc=*(const h8*)&combo[(pk>>16)*DIM+l*8];
        a+=sv+cc;
      }
    }
    *(h8*)&agg[(size_t)(n-n0)*DIM+l*8]=a;
  }
}

// ---- fp16 GEMM, 2-phase double-buffered LDS + XOR-swizzle + setprio ----
// C = act(A[MxK]*B[NxK]^T + bias); optional fused BN-stats
template<int RELU,int STATS>
__global__ __launch_bounds__(256) void gemm_f16(
    const u16* __restrict__ A, int lda,
    const u16* __restrict__ B, int ldb,
    const float* __restrict__ bias,
    u16* __restrict__ C, int ldc, int K,
    float* __restrict__ stats, int rowlim)
{
  __shared__ u16 sm[2*16384] __attribute__((aligned(16)));   // [buf][A:8192 | B:8192] f16
  __shared__ float sS[128], sQ[128];
  int t=threadIdx.x, w=t>>6, l=t&63;
  if(STATS){ if(t<128) sS[t]=0.f; else sQ[t-128]=0.f; }
  // T1: bijective XCD-aware remap
  int nwg=(int)(gridDim.x*gridDim.y);
  int orig=(int)(blockIdx.y*gridDim.x+blockIdx.x);
  int q=nwg>>3, r=nwg&7, xcd=orig&7, ii=orig>>3;
  int swz=(xcd<r ? xcd*(q+1) : r*(q+1)+(xcd-r)*q) + ii;
  int bx=swz%(int)gridDim.x, by=swz/(int)gridDim.x;
  size_t col0=(size_t)bx*128, row0=(size_t)by*128;
  int wr=w>>1, wc=w&1;
  int lr=l&15, kb=l>>4, lsw=lr&7;

  // stage K-tile k0 into buffer cur: LDS dest linear, global source chunk-XOR-swizzled (rule #21)
  auto STAGE=[&](int cur,int k0){
    u16* base=sm+cur*16384;
    #pragma unroll
    for(int i=0;i<4;++i){
      int c=i*256+t, rr=c>>3, c8=c&7, c8s=c8^(rr&7);
      __builtin_amdgcn_global_load_lds(
        (const __attribute__((address_space(1))) void*)(A+(row0+rr)*lda+(size_t)k0+c8s*8),
        (__attribute__((address_space(3))) void*)(base+(size_t)(i*256+(w<<6))*8), 16,0,0);
      __builtin_amdgcn_global_load_lds(
        (const __attribute__((address_space(1))) void*)(B+(col0+rr)*ldb+(size_t)k0+c8s*8),
        (__attribute__((address_space(3))) void*)(base+8192+(size_t)(i*256+(w<<6))*8), 16,0,0);
    }
  };

  f32x4 acc[4][4]={};
  int nt=K>>6;
  STAGE(0,0);
  asm volatile("s_waitcnt vmcnt(0) lgkmcnt(0)" ::: "memory");
  __builtin_amdgcn_s_barrier();
  int cur=0;
  for(int tile=0;tile<nt;++tile){
    if(tile+1<nt) STAGE(cur^1,(tile+1)<<6);
    const u16* Ab=sm+cur*16384;
    const u16* Bb=Ab+8192;
    #pragma unroll
    for(int kk=0;kk<2;++kk){
      int ch=(kk*4+kb);
      h8 av[4],bv[4];
      #pragma unroll
      for(int m=0;m<4;++m) av[m]=*(const h8*)(Ab+(size_t)(wr*64+m*16+lr)*64+(size_t)((ch^lsw)*8));
      #pragma unroll
      for(int n=0;n<4;++n) bv[n]=*(const h8*)(Bb+(size_t)(wc*64+n*16+lr)*64+(size_t)((ch^lsw)*8));
      __builtin_amdgcn_s_setprio(1);
      #pragma unroll
      for(int m=0;m<4;++m)
        #pragma unroll
        for(int n=0;n<4;++n)
          acc[m][n]=__builtin_amdgcn_mfma_f32_16x16x32_f16(av[m],bv[n],acc[m][n],0,0,0);
      __builtin_amdgcn_s_setprio(0);
    }
    asm volatile("s_waitcnt vmcnt(0)" ::: "memory");   // wait next tile's loads (issued before compute)
    __builtin_amdgcn_s_barrier();
    __builtin_amdgcn_sched_barrier(0);
    cur^=1;
  }
  #pragma unroll
  for(int n=0;n<4;++n){
    int col=(int)col0+wc*64+n*16+lr;
    float bcol=bias[col];
    float cs=0.f, cq=0.f;
    #pragma unroll
    for(int m=0;m<4;++m){
      int rowb=(int)row0+wr*64+m*16+(kb*4);
      #pragma unroll
      for(int rr=0;rr<4;++rr){
        float v=acc[m][n][rr]+bcol;
        if(RELU) v=fmaxf(v,0.f);
        C[(size_t)(rowb+rr)*ldc+col]=f2h(v);
        if(STATS){ if(rowb+rr<rowlim){ cs+=v; cq+=v*v; } }
      }
    }
    if(STATS){
      cs+=__shfl_xor(cs,16); cs+=__shfl_xor(cs,32);
      cq+=__shfl_xor(cq,16); cq+=__shfl_xor(cq,32);
      if(kb==0){
        atomicAdd(&sS[wc*64+n*16+lr],cs);
        atomicAdd(&sQ[wc*64+n*16+lr],cq);
      }
    }
  }
  if(STATS){
    __syncthreads();
    if(t<128) atomicAdd(&stats[col0+t], sS[t]);
    else      atomicAdd(&stats[DIM+col0+(t-128)], sQ[t-128]);
  }
}

// ---- BN apply + relu (finalize fused): one wave per row, affine in registers ----
__global__ void bn_apply(const u16* __restrict__ h2, const float* __restrict__ stats,
    const float* __restrict__ gamma, const float* __restrict__ beta, u16* __restrict__ h){
  int w=threadIdx.x>>6, l=threadIdx.x&63;
  h8 scv, shv;
  #pragma unroll
  for(int j=0;j<8;++j){
    int d=l*8+j;
    float mu=stats[d]*(1.f/NNODES);
    float var=stats[DIM+d]*(1.f/NNODES)-mu*mu;
    float sc=gamma[d]*rsqrtf(var+1e-5f);
    scv[j]=(f16)sc; shv[j]=(f16)(beta[d]-mu*sc);
  }
  for(int n=blockIdx.x*4+w; n<NNODES; n+=gridDim.x*4){
    size_t o=(size_t)n*DIM+l*8;
    h8 v=*(const h8*)&h2[o];
    h8 x=v*scv+shv;
    s16x8 xi=__builtin_bit_cast(s16x8,x);
    #pragma unroll
    for(int j=0;j<8;++j) xi[j]=(xi[j]<0)?0:xi[j];   // relu via sign bit
    *(s16x8*)&h[o]=xi;
  }
}

// ---- graph pooling with fused BN affine (finalize fused, no relu): one wave per graph ----
__global__ void batch_reduce(const u16* __restrict__ h2, const float* __restrict__ stats,
    const float* __restrict__ gamma, const float* __restrict__ beta,
    const int* __restrict__ browptr, const u16* __restrict__ bnodes, u16* __restrict__ z){
  int w=threadIdx.x>>6, l=threadIdx.x&63;
  int g=blockIdx.x*4+w;
  if(g>=NGRAPH) return;
  float sc[8], sh[8];
  #pragma unroll
  for(int j=0;j<8;++j){
    int d=l*8+j;
    float mu=stats[d]*(1.f/NNODES);
    float var=stats[DIM+d]*(1.f/NNODES)-mu*mu;
    sc[j]=gamma[d]*rsqrtf(var+1e-5f);
    sh[j]=beta[d]-mu*sc[j];
  }
  float a[8]={0,0,0,0,0,0,0,0};
  int pe=browptr[g+1];
  for(int p=browptr[g];p<pe;++p){
    int n=bnodes[p];
    h8 v=*(const h8*)&h2[(size_t)n*DIM + l*8];
    #pragma unroll
    for(int j=0;j<8;++j) a[j]+=sc[j]*(float)v[j]+sh[j];
  }
  s16x8 o;
  #pragma unroll
  for(int j=0;j<8;++j) o[j]=(short)f2h(a[j]);
  *(s16x8*)&z[(size_t)g*1024 + l*8]=o;
}

// ---------------- last layer: dot(128) + bias ----------------
__global__ void last_kernel(const u16* __restrict__ z2, const float* __restrict__ lw,
    const float* __restrict__ lb, float* __restrict__ out){
  int g=blockIdx.x*4+(threadIdx.x>>6), l=threadIdx.x&63;
  float a=h2f(z2[g*128+l])*lw[l]+h2f(z2[g*128+64+l])*lw[64+l];
  #pragma unroll
  for(int off=32;off;off>>=1) a+=__shfl_down(a,off,64);
  if(l==0) out[g]=a+lb[0];
}

extern "C" void kernel_launch(void* const* d_in, const int* in_sizes, int n_in,
                              void* d_out, int out_size, void* d_ws, size_t ws_size,
                              hipStream_t stream){
  (void)in_sizes; (void)n_in; (void)out_size;
  const float* solute_x =(const float*)d_in[0];
  const float* solvent_x=(const float*)d_in[1];
  const int*   eidx     =(const int*)d_in[2];
  const int*   eattr    =(const int*)d_in[3];
  const int*   batch    =(const int*)d_in[4];
  const float* xembW=(const float*)d_in[5];
  const float* xembB=(const float*)d_in[6];
  const float* m1W=(const float*)d_in[7];
  const float* m1b=(const float*)d_in[8];
  const float* m2W=(const float*)d_in[9];
  const float* m2b=(const float*)d_in[10];
  const float* ee1=(const float*)d_in[11];
  const float* ee2=(const float*)d_in[12];
  const float* gam=(const float*)d_in[13];
  const float* bet=(const float*)d_in[14];
  const float* sW1=(const float*)d_in[15];
  const float* sb1=(const float*)d_in[16];
  const float* sW2=(const float*)d_in[17];
  const float* sb2=(const float*)d_in[18];
  const float* oW0=(const float*)d_in[19];
  const float* ob0=(const float*)d_in[20];
  const float* oW1=(const float*)d_in[21];
  const float* ob1=(const float*)d_in[22];
  const float* oW2=(const float*)d_in[23];
  const float* ob2=(const float*)d_in[24];
  const float* lW =(const float*)d_in[25];
  const float* lb =(const float*)d_in[26];
  float* out=(float*)d_out;

  char* p=(char*)d_ws; size_t off=0;
  auto alloc=[&](size_t b)->void*{ void* q=p+off; off+=(b+255)&~(size_t)255; return q; };
  u16* h_f   =(u16*)alloc((size_t)NPAD*DIM*2);
  u16* h2_f  =(u16*)alloc((size_t)NPAD*DIM*2);
  u16* W1t =(u16*)alloc((size_t)NLAYER*1024*512*2);
  u16* W2t =(u16*)alloc((size_t)NLAYER*512*1024*2);
  u16* sW2t=(u16*)alloc((size_t)512*512*2);
  u16* oW0t=(u16*)alloc((size_t)512*1024*2);
  u16* oW1t=(u16*)alloc((size_t)256*512*2);
  u16* oW2t=(u16*)alloc((size_t)128*256*2);
  u16* s1 =(u16*)alloc((size_t)NGRAPH*512*2);
  u16* z  =(u16*)alloc((size_t)NGRAPH*1024*2);
  u16* z0 =(u16*)alloc((size_t)NGRAPH*512*2);
  u16* z1 =(u16*)alloc((size_t)NGRAPH*256*2);
  u16* z2 =(u16*)alloc((size_t)NGRAPH*128*2);
  float* stats=(float*)alloc((size_t)NLAYER*2*DIM*4);   // per-layer raw sum/sumsq
  int* rowptr =(int*)alloc((size_t)(NNODES+1)*4);
  int* degcnt =(int*)alloc((size_t)NNODES*4);
  u32* es_pk  =(u32*)alloc((size_t)NEDGES*4);
  int* bdeg   =(int*)alloc((size_t)NGRAPH*4);
  int* browptr=(int*)alloc((size_t)(NGRAPH+1)*4);
  int* bcnt   =(int*)alloc((size_t)NGRAPH*4);
  u16* bnodes =(u16*)alloc((size_t)NNODES*2);

  const size_t per_chb=(size_t)128*512*2 + (size_t)128*1024*2;
  size_t left = ws_size>off+4096 ? ws_size-off-4096 : 0;
  int chb=(int)(left/per_chb);
  if(chb<1) return;
  if(chb>NBLK) chb=NBLK;
  u16* agg_c=(u16*)alloc((size_t)chb*128*512*2);
  u16* t_c  =(u16*)alloc((size_t)chb*128*1024*2);

  // ---- weight transposes ----
  transpose_bt<<<dim3(32,16,NLAYER),256,0,stream>>>(m1W, W1t, 512,1024, (size_t)512*1024, (size_t)1024*512);
  transpose_bt<<<dim3(16,32,NLAYER),256,0,stream>>>(m2W, W2t, 1024,512, (size_t)1024*512, (size_t)512*1024);
  transpose_bt<<<dim3(16,16,1),256,0,stream>>>(sW2, sW2t, 512,512, 0,0);
  transpose_bt<<<dim3(16,32,1),256,0,stream>>>(oW0, oW0t, 1024,512, 0,0);
  transpose_bt<<<dim3(8,16,1),256,0,stream>>>(oW1, oW1t, 512,256, 0,0);
  transpose_bt<<<dim3(4,8,1),256,0,stream>>>(oW2, oW2t, 256,128, 0,0);

  // ---- embed + all-layer stats clear ----
  dense40<<<1024,256,0,stream>>>(solute_x, xembW, xembB, h_f, NNODES, NPAD);
  hipMemsetAsync(stats,0,(size_t)NLAYER*2*DIM*4,stream);

  // ---- edge CSR ----
  hipMemsetAsync(degcnt,0,(size_t)NNODES*4,stream);
  hist_kernel<<<(NEDGES+255)/256,256,0,stream>>>(eidx+NEDGES, degcnt, NEDGES);
  {
    int nb=(NNODES+255)/256;
    block_sums<<<nb,256,0,stream>>>(degcnt, bdeg, NNODES);
    scan_partials<<<1,256,0,stream>>>(bdeg, nb);
    scan_write<<<nb,256,0,stream>>>(degcnt, bdeg, rowptr, NNODES);
  }
  hipMemsetAsync(degcnt,0,(size_t)NNODES*4,stream);
  scatter_edges<<<(NEDGES+255)/256,256,0,stream>>>(eidx, eattr, rowptr, degcnt, es_pk);

  // ---- batch CSR ----
  hipMemsetAsync(bdeg,0,(size_t)NGRAPH*4,stream);
  hist_kernel<<<(NNODES+255)/256,256,0,stream>>>(batch, bdeg, NNODES);
  {
    int nb=(NGRAPH+255)/256;
    block_sums<<<nb,256,0,stream>>>(bdeg, bcnt, NGRAPH);
    scan_partials<<<1,256,0,stream>>>(bcnt, nb);
    scan_write<<<nb,256,0,stream>>>(bdeg, bcnt, browptr, NGRAPH);
  }
  hipMemsetAsync(bcnt,0,(size_t)NGRAPH*4,stream);
  scatter_batch<<<(NNODES+255)/256,256,0,stream>>>(batch, browptr, bcnt, bnodes);

  // ---- GNN layers ----
  for(int l=0;l<NLAYER;++l){
    const float* e1=ee1+(size_t)l*6*DIM;
    const float* e2=ee2+(size_t)l*3*DIM;
    float* st=stats+(size_t)l*2*DIM;
    for(int b0=0;b0<NBLK;b0+=chb){
      int nb=NBLK-b0; if(nb>chb) nb=chb;
      int n0=b0*128, rows=nb*128;
      agg_kernel<<<2048,256,0,stream>>>(h_f, rowptr, es_pk, e1, e2, agg_c, n0, n0+rows);
      gemm_f16<1,0><<<dim3(8,nb),256,0,stream>>>(agg_c, 512, W1t+(size_t)l*1024*512, 512,
          m1b+(size_t)l*1024, t_c, 1024, 512, nullptr, 1<<30);
      gemm_f16<0,1><<<dim3(4,nb),256,0,stream>>>(t_c, 1024, W2t+(size_t)l*512*1024, 1024,
          m2b+(size_t)l*512, h2_f+(size_t)n0*DIM, 512, 1024, st, NNODES-n0);
    }
    if(l<NLAYER-1)
      bn_apply<<<2048,256,0,stream>>>(h2_f, st, gam+(size_t)l*DIM, bet+(size_t)l*DIM, h_f);
  }

  // ---- pooling (layer-4 BN fused) + solvent + readout ----
  batch_reduce<<<512,256,0,stream>>>(h2_f, stats+(size_t)(NLAYER-1)*2*DIM,
      gam+(size_t)(NLAYER-1)*DIM, bet+(size_t)(NLAYER-1)*DIM, browptr, bnodes, z);
  dense40<<<1024,256,0,stream>>>(solvent_x, sW1, sb1, s1, NGRAPH, NGRAPH);
  gemm_f16<0,0><<<dim3(4,16),256,0,stream>>>(s1, 512, sW2t, 512, sb2, z+512, 1024, 512, nullptr, 1<<30);
  gemm_f16<1,0><<<dim3(4,16),256,0,stream>>>(z, 1024, oW0t, 1024, ob0, z0, 512, 1024, nullptr, 1<<30);
  gemm_f16<1,0><<<dim3(2,16),256,0,stream>>>(z0, 512, oW1t, 512, ob1, z1, 256, 512, nullptr, 1<<30);
  gemm_f16<1,0><<<dim3(1,16),256,0,stream>>>(z1, 256, oW2t, 256, ob2, z2, 128, 256, nullptr, 1<<30);
  last_kernel<<<NGRAPH/4,256,0,stream>>>(z2, lW, lb, out);
}

// Round 10
// 1431.662 us; speedup vs baseline: 1.7011x; 1.0178x over previous
//
#include <hip/hip_runtime.h>

#define NNODES 60000
#define NPAD   60032
#define NBLK   469      // NPAD/128
#define NEDGES 150000
#define NGRAPH 2048
#define DIM    512
#define NLAYER 5

typedef unsigned short u16;
typedef unsigned int   u32;
typedef _Float16 f16;
typedef __attribute__((ext_vector_type(8))) _Float16 h8;
typedef __attribute__((ext_vector_type(8))) short s16x8;
typedef __attribute__((ext_vector_type(4))) float f32x4;
typedef __attribute__((ext_vector_type(4))) float float4v;

__device__ __forceinline__ float h2f(u16 u){ return (float)__builtin_bit_cast(f16,u); }
__device__ __forceinline__ u16 f2h(float f){ return __builtin_bit_cast(u16,(f16)f); }

// ---------------- transpose fp32 KxN -> fp16 NxK (z = layer) ----------------
__global__ void transpose_bt(const float* __restrict__ W, u16* __restrict__ Wt, int K, int N,
                             size_t strideW, size_t strideWt){
  const float* Wz=W+(size_t)blockIdx.z*strideW;
  u16* Wtz=Wt+(size_t)blockIdx.z*strideWt;
  __shared__ float tile[32][33];
  int bx=blockIdx.x*32, by=blockIdx.y*32;
  int tx=threadIdx.x&31, ty=threadIdx.x>>5;
  for(int i=ty;i<32;i+=8) tile[i][tx]=Wz[(size_t)(by+i)*N + bx+tx];
  __syncthreads();
  for(int i=ty;i<32;i+=8) Wtz[(size_t)(bx+i)*K + by+tx]=f2h(tile[tx][i]);
}

// ---- fp32 MxK(=40) -> fp16 Mpad x 64 zero-padded ----
__global__ void cvt_pad(const float* __restrict__ X, u16* __restrict__ Y, int M, int Mpad){
  int idx=blockIdx.x*256+threadIdx.x;          // Mpad*8 threads
  int r=idx>>3, g=(idx&7)*8;
  if(r>=Mpad) return;
  s16x8 o={};
  if(r<M && g<40){
    float4v v0=*(const float4v*)&X[(size_t)r*40+g];
    float4v v1=*(const float4v*)&X[(size_t)r*40+g+4];
    #pragma unroll
    for(int j=0;j<4;++j){ o[j]=(short)f2h(v0[j]); o[4+j]=(short)f2h(v1[j]); }
  }
  *(s16x8*)&Y[(size_t)r*64+g]=o;
}

// ---- weight 40xN fp32 -> fp16 N x 64 (K padded) ----
__global__ void prep_w40(const float* __restrict__ W, u16* __restrict__ Wt, int N){
  int idx=blockIdx.x*256+threadIdx.x;          // N*64 threads
  if(idx>=N*64) return;
  int n=idx>>6, k=idx&63;
  Wt[idx]= (k<40)? f2h(W[(size_t)k*N+n]) : (u16)0;
}

// ---------------- CSR build ----------------
__global__ void hist_kernel(const int* __restrict__ idx, int* __restrict__ cnt, int n){
  int i=blockIdx.x*256+threadIdx.x;
  if(i<n) atomicAdd(&cnt[idx[i]],1);
}

__global__ void block_sums(const int* __restrict__ in, int* __restrict__ psum, int n){
  __shared__ int s[256];
  int i=blockIdx.x*256+threadIdx.x;
  s[threadIdx.x]=(i<n)?in[i]:0;
  __syncthreads();
  for(int o=128;o;o>>=1){ if(threadIdx.x<o) s[threadIdx.x]+=s[threadIdx.x+o]; __syncthreads(); }
  if(threadIdx.x==0) psum[blockIdx.x]=s[0];
}
__global__ void scan_partials(int* __restrict__ psum, int nb){
  __shared__ int s[256];
  int t=threadIdx.x;
  s[t]=(t<nb)?psum[t]:0;
  __syncthreads();
  for(int o=1;o<256;o<<=1){
    int v=(t>=o)?s[t-o]:0;
    __syncthreads();
    s[t]+=v;
    __syncthreads();
  }
  if(t<nb) psum[t]= t? s[t-1]:0;
}
__global__ void scan_write(const int* __restrict__ in, const int* __restrict__ psum,
                           int* __restrict__ out, int n){
  __shared__ int s[256];
  int t=threadIdx.x;
  int i=blockIdx.x*256+t;
  s[t]=(i<n)?in[i]:0;
  __syncthreads();
  for(int o=1;o<256;o<<=1){
    int v=(t>=o)?s[t-o]:0;
    __syncthreads();
    s[t]+=v;
    __syncthreads();
  }
  if(i<n) out[i+1]=psum[blockIdx.x]+s[t];
  if(i==0) out[0]=0;
}

// single-block exclusive scan for n<=2048 (batch rowptr)
__global__ void scan2048(const int* __restrict__ in, int* __restrict__ out, int n){
  __shared__ int buf[1024];
  int t=threadIdx.x;
  int a=(2*t<n)?in[2*t]:0, b=(2*t+1<n)?in[2*t+1]:0;
  buf[t]=a+b;
  __syncthreads();
  for(int o=1;o<1024;o<<=1){
    int v=(t>=o)?buf[t-o]:0;
    __syncthreads();
    buf[t]+=v;
    __syncthreads();
  }
  int excl=buf[t]-(a+b);
  if(2*t<n)   out[2*t+1]=excl+a;
  if(2*t+1<n) out[2*t+2]=excl+a+b;
  if(t==0) out[0]=0;
}

__global__ void scatter_edges(const int* __restrict__ eidx, const int* __restrict__ eattr,
                              const int* __restrict__ rowptr, int* __restrict__ cnt,
                              u32* __restrict__ es_pk){
  int e=blockIdx.x*256+threadIdx.x;
  if(e>=NEDGES) return;
  int s=eidx[e], d=eidx[NEDGES+e];
  int pos=rowptr[d]+atomicAdd(&cnt[d],1);
  es_pk[pos]=(u32)s | ((u32)(eattr[2*e]*3+eattr[2*e+1])<<16);
}

__global__ void scatter_batch(const int* __restrict__ batch, const int* __restrict__ browptr,
                              int* __restrict__ bcnt, u16* __restrict__ bnodes){
  int n=blockIdx.x*256+threadIdx.x;
  if(n>=NNODES) return;
  int g=batch[n];
  int pos=browptr[g]+atomicAdd(&bcnt[g],1);
  bnodes[pos]=(u16)n;
}

// ---- aggregate: one WAVE per node row; packed fp16 adds; combo fp16 in LDS (1 b128/edge) ----
__global__ void agg_kernel(const u16* __restrict__ h, const int* __restrict__ rowptr,
    const u32* __restrict__ es_pk, const float* __restrict__ emb1, const float* __restrict__ emb2,
    u16* __restrict__ agg, int n0, int n1){
  __shared__ u16 combo[10*DIM];
  for(int i=threadIdx.x;i<10*DIM;i+=256){
    int c=i>>9, d=i&(DIM-1);
    int bt=(c<9)?(c/3):4, bd=(c<9)?(c%3):0;
    combo[c*DIM+d]=f2h(emb1[bt*DIM+d]+emb2[bd*DIM+d]);
  }
  __syncthreads();
  int w=threadIdx.x>>6, l=threadIdx.x&63;
  const h8 cb9=*(const h8*)&combo[9*DIM+l*8];
  for(int n=n0+blockIdx.x*4+w; n<n1; n+=gridDim.x*4){
    h8 a={};
    if(n<NNODES){
      a=*(const h8*)&h[(size_t)n*DIM+l*8] + cb9;
      int pe=rowptr[n+1];
      for(int p=rowptr[n];p<pe;++p){
        u32 pk=es_pk[p];
        h8 sv=*(const h8*)&h[(size_t)(pk&0xFFFFu)*DIM+l*8];
        h8 cc=*(const h8*)&combo[(pk>>16)*DIM+l*8];
        a+=sv+cc;
      }
    }
    *(h8*)&agg[(size_t)(n-n0)*DIM+l*8]=a;
  }
}

// ---- fp16 GEMM, 2-phase double-buffered LDS + XOR-swizzle + setprio ----
template<int RELU,int STATS>
__global__ __launch_bounds__(256) void gemm_f16(
    const u16* __restrict__ A, int lda,
    const u16* __restrict__ B, int ldb,
    const float* __restrict__ bias,
    u16* __restrict__ C, int ldc, int K,
    float* __restrict__ stats, int rowlim)
{
  __shared__ u16 sm[2*16384] __attribute__((aligned(16)));   // [buf][A:8192 | B:8192] f16
  __shared__ float sS[128], sQ[128];
  int t=threadIdx.x, w=t>>6, l=t&63;
  if(STATS){ if(t<128) sS[t]=0.f; else sQ[t-128]=0.f; }
  // T1: bijective XCD-aware remap
  int nwg=(int)(gridDim.x*gridDim.y);
  int orig=(int)(blockIdx.y*gridDim.x+blockIdx.x);
  int q=nwg>>3, r=nwg&7, xcd=orig&7, ii=orig>>3;
  int swz=(xcd<r ? xcd*(q+1) : r*(q+1)+(xcd-r)*q) + ii;
  int bx=swz%(int)gridDim.x, by=swz/(int)gridDim.x;
  size_t col0=(size_t)bx*128, row0=(size_t)by*128;
  int wr=w>>1, wc=w&1;
  int lr=l&15, kb=l>>4, lsw=lr&7;

  auto STAGE=[&](int cur,int k0){
    u16* base=sm+cur*16384;
    #pragma unroll
    for(int i=0;i<4;++i){
      int c=i*256+t, rr=c>>3, c8=c&7, c8s=c8^(rr&7);
      __builtin_amdgcn_global_load_lds(
        (const __attribute__((address_space(1))) void*)(A+(row0+rr)*lda+(size_t)k0+c8s*8),
        (__attribute__((address_space(3))) void*)(base+(size_t)(i*256+(w<<6))*8), 16,0,0);
      __builtin_amdgcn_global_load_lds(
        (const __attribute__((address_space(1))) void*)(B+(col0+rr)*ldb+(size_t)k0+c8s*8),
        (__attribute__((address_space(3))) void*)(base+8192+(size_t)(i*256+(w<<6))*8), 16,0,0);
    }
  };

  f32x4 acc[4][4]={};
  int nt=K>>6;
  STAGE(0,0);
  asm volatile("s_waitcnt vmcnt(0) lgkmcnt(0)" ::: "memory");
  __builtin_amdgcn_s_barrier();
  int cur=0;
  for(int tile=0;tile<nt;++tile){
    if(tile+1<nt) STAGE(cur^1,(tile+1)<<6);
    const u16* Ab=sm+cur*16384;
    const u16* Bb=Ab+8192;
    #pragma unroll
    for(int kk=0;kk<2;++kk){
      int ch=(kk*4+kb);
      h8 av[4],bv[4];
      #pragma unroll
      for(int m=0;m<4;++m) av[m]=*(const h8*)(Ab+(size_t)(wr*64+m*16+lr)*64+(size_t)((ch^lsw)*8));
      #pragma unroll
      for(int n=0;n<4;++n) bv[n]=*(const h8*)(Bb+(size_t)(wc*64+n*16+lr)*64+(size_t)((ch^lsw)*8));
      __builtin_amdgcn_s_setprio(1);
      #pragma unroll
      for(int m=0;m<4;++m)
        #pragma unroll
        for(int n=0;n<4;++n)
          acc[m][n]=__builtin_amdgcn_mfma_f32_16x16x32_f16(av[m],bv[n],acc[m][n],0,0,0);
      __builtin_amdgcn_s_setprio(0);
    }
    asm volatile("s_waitcnt vmcnt(0)" ::: "memory");
    __builtin_amdgcn_s_barrier();
    __builtin_amdgcn_sched_barrier(0);
    cur^=1;
  }
  #pragma unroll
  for(int n=0;n<4;++n){
    int col=(int)col0+wc*64+n*16+lr;
    float bcol=bias[col];
    float cs=0.f, cq=0.f;
    #pragma unroll
    for(int m=0;m<4;++m){
      int rowb=(int)row0+wr*64+m*16+(kb*4);
      #pragma unroll
      for(int rr=0;rr<4;++rr){
        float v=acc[m][n][rr]+bcol;
        if(RELU) v=fmaxf(v,0.f);
        C[(size_t)(rowb+rr)*ldc+col]=f2h(v);
        if(STATS){ if(rowb+rr<rowlim){ cs+=v; cq+=v*v; } }
      }
    }
    if(STATS){
      cs+=__shfl_xor(cs,16); cs+=__shfl_xor(cs,32);
      cq+=__shfl_xor(cq,16); cq+=__shfl_xor(cq,32);
      if(kb==0){
        atomicAdd(&sS[wc*64+n*16+lr],cs);
        atomicAdd(&sQ[wc*64+n*16+lr],cq);
      }
    }
  }
  if(STATS){
    __syncthreads();
    if(t<128) atomicAdd(&stats[col0+t], sS[t]);
    else      atomicAdd(&stats[DIM+col0+(t-128)], sQ[t-128]);
  }
}

// ---- BN apply + relu (finalize fused): one wave per row, affine in registers ----
__global__ void bn_apply(const u16* __restrict__ h2, const float* __restrict__ stats,
    const float* __restrict__ gamma, const float* __restrict__ beta, u16* __restrict__ h){
  int w=threadIdx.x>>6, l=threadIdx.x&63;
  h8 scv, shv;
  #pragma unroll
  for(int j=0;j<8;++j){
    int d=l*8+j;
    float mu=stats[d]*(1.f/NNODES);
    float var=stats[DIM+d]*(1.f/NNODES)-mu*mu;
    float sc=gamma[d]*rsqrtf(var+1e-5f);
    scv[j]=(f16)sc; shv[j]=(f16)(beta[d]-mu*sc);
  }
  for(int n=blockIdx.x*4+w; n<NNODES; n+=gridDim.x*4){
    size_t o=(size_t)n*DIM+l*8;
    h8 v=*(const h8*)&h2[o];
    h8 x=v*scv+shv;
    s16x8 xi=__builtin_bit_cast(s16x8,x);
    #pragma unroll
    for(int j=0;j<8;++j) xi[j]=(xi[j]<0)?0:xi[j];
    *(s16x8*)&h[o]=xi;
  }
}

// ---- graph pooling with fused BN affine: one wave per graph ----
__global__ void batch_reduce(const u16* __restrict__ h2, const float* __restrict__ stats,
    const float* __restrict__ gamma, const float* __restrict__ beta,
    const int* __restrict__ browptr, const u16* __restrict__ bnodes, u16* __restrict__ z){
  int w=threadIdx.x>>6, l=threadIdx.x&63;
  int g=blockIdx.x*4+w;
  if(g>=NGRAPH) return;
  float sc[8], sh[8];
  #pragma unroll
  for(int j=0;j<8;++j){
    int d=l*8+j;
    float mu=stats[d]*(1.f/NNODES);
    float var=stats[DIM+d]*(1.f/NNODES)-mu*mu;
    sc[j]=gamma[d]*rsqrtf(var+1e-5f);
    sh[j]=beta[d]-mu*sc[j];
  }
  float a[8]={0,0,0,0,0,0,0,0};
  int pe=browptr[g+1];
  for(int p=browptr[g];p<pe;++p){
    int n=bnodes[p];
    h8 v=*(const h8*)&h2[(size_t)n*DIM + l*8];
    #pragma unroll
    for(int j=0;j<8;++j) a[j]+=sc[j]*(float)v[j]+sh[j];
  }
  s16x8 o;
  #pragma unroll
  for(int j=0;j<8;++j) o[j]=(short)f2h(a[j]);
  *(s16x8*)&z[(size_t)g*1024 + l*8]=o;
}

// ---------------- last layer: dot(128) + bias ----------------
__global__ void last_kernel(const u16* __restrict__ z2, const float* __restrict__ lw,
    const float* __restrict__ lb, float* __restrict__ out){
  int g=blockIdx.x*4+(threadIdx.x>>6), l=threadIdx.x&63;
  float a=h2f(z2[g*128+l])*lw[l]+h2f(z2[g*128+64+l])*lw[64+l];
  #pragma unroll
  for(int off=32;off;off>>=1) a+=__shfl_down(a,off,64);
  if(l==0) out[g]=a+lb[0];
}

extern "C" void kernel_launch(void* const* d_in, const int* in_sizes, int n_in,
                              void* d_out, int out_size, void* d_ws, size_t ws_size,
                              hipStream_t stream){
  (void)in_sizes; (void)n_in; (void)out_size;
  const float* solute_x =(const float*)d_in[0];
  const float* solvent_x=(const float*)d_in[1];
  const int*   eidx     =(const int*)d_in[2];
  const int*   eattr    =(const int*)d_in[3];
  const int*   batch    =(const int*)d_in[4];
  const float* xembW=(const float*)d_in[5];
  const float* xembB=(const float*)d_in[6];
  const float* m1W=(const float*)d_in[7];
  const float* m1b=(const float*)d_in[8];
  const float* m2W=(const float*)d_in[9];
  const float* m2b=(const float*)d_in[10];
  const float* ee1=(const float*)d_in[11];
  const float* ee2=(const float*)d_in[12];
  const float* gam=(const float*)d_in[13];
  const float* bet=(const float*)d_in[14];
  const float* sW1=(const float*)d_in[15];
  const float* sb1=(const float*)d_in[16];
  const float* sW2=(const float*)d_in[17];
  const float* sb2=(const float*)d_in[18];
  const float* oW0=(const float*)d_in[19];
  const float* ob0=(const float*)d_in[20];
  const float* oW1=(const float*)d_in[21];
  const float* ob1=(const float*)d_in[22];
  const float* oW2=(const float*)d_in[23];
  const float* ob2=(const float*)d_in[24];
  const float* lW =(const float*)d_in[25];
  const float* lb =(const float*)d_in[26];
  float* out=(float*)d_out;

  char* p=(char*)d_ws; size_t off=0;
  auto alloc=[&](size_t b)->void*{ void* q=p+off; off+=(b+255)&~(size_t)255; return q; };
  u16* h_f   =(u16*)alloc((size_t)NPAD*DIM*2);
  u16* h2_f  =(u16*)alloc((size_t)NPAD*DIM*2);
  u16* xa16  =(u16*)alloc((size_t)NPAD*64*2);
  u16* sv16  =(u16*)alloc((size_t)NGRAPH*64*2);
  u16* wx16  =(u16*)alloc((size_t)512*64*2);
  u16* ws1t  =(u16*)alloc((size_t)512*64*2);
  u16* W1t =(u16*)alloc((size_t)NLAYER*1024*512*2);
  u16* W2t =(u16*)alloc((size_t)NLAYER*512*1024*2);
  u16* sW2t=(u16*)alloc((size_t)512*512*2);
  u16* oW0t=(u16*)alloc((size_t)512*1024*2);
  u16* oW1t=(u16*)alloc((size_t)256*512*2);
  u16* oW2t=(u16*)alloc((size_t)128*256*2);
  u16* s1 =(u16*)alloc((size_t)NGRAPH*512*2);
  u16* z  =(u16*)alloc((size_t)NGRAPH*1024*2);
  u16* z0 =(u16*)alloc((size_t)NGRAPH*512*2);
  u16* z1 =(u16*)alloc((size_t)NGRAPH*256*2);
  u16* z2 =(u16*)alloc((size_t)NGRAPH*128*2);
  float* stats=(float*)alloc((size_t)NLAYER*2*DIM*4);
  int* rowptr =(int*)alloc((size_t)(NNODES+1)*4);
  int* deg    =(int*)alloc((size_t)NNODES*4);
  int* cnt2   =(int*)alloc((size_t)NNODES*4);
  u32* es_pk  =(u32*)alloc((size_t)NEDGES*4);
  int* browptr=(int*)alloc((size_t)(NGRAPH+1)*4);
  int* bdeg   =(int*)alloc((size_t)NGRAPH*4);
  int* bcnt   =(int*)alloc((size_t)NGRAPH*4);
  u16* bnodes =(u16*)alloc((size_t)NNODES*2);

  const size_t per_chb=(size_t)128*512*2 + (size_t)128*1024*2;
  size_t left = ws_size>off+4096 ? ws_size-off-4096 : 0;
  int chb=(int)(left/per_chb);
  if(chb<1) return;
  if(chb>NBLK) chb=NBLK;
  u16* agg_c=(u16*)alloc((size_t)chb*128*512*2);
  u16* t_c  =(u16*)alloc((size_t)chb*128*1024*2);

  const size_t degpad=((size_t)NNODES*4+255)&~(size_t)255;

  // ---- weight prep ----
  transpose_bt<<<dim3(32,16,NLAYER),256,0,stream>>>(m1W, W1t, 512,1024, (size_t)512*1024, (size_t)1024*512);
  transpose_bt<<<dim3(16,32,NLAYER),256,0,stream>>>(m2W, W2t, 1024,512, (size_t)1024*512, (size_t)512*1024);
  transpose_bt<<<dim3(16,16,1),256,0,stream>>>(sW2, sW2t, 512,512, 0,0);
  transpose_bt<<<dim3(16,32,1),256,0,stream>>>(oW0, oW0t, 1024,512, 0,0);
  transpose_bt<<<dim3(8,16,1),256,0,stream>>>(oW1, oW1t, 512,256, 0,0);
  transpose_bt<<<dim3(4,8,1),256,0,stream>>>(oW2, oW2t, 256,128, 0,0);
  prep_w40<<<128,256,0,stream>>>(xembW, wx16, 512);
  prep_w40<<<128,256,0,stream>>>(sW1, ws1t, 512);

  // ---- inputs -> fp16 padded + embed GEMM ----
  cvt_pad<<<(NPAD*8)/256,256,0,stream>>>(solute_x, xa16, NNODES, NPAD);
  cvt_pad<<<(NGRAPH*8)/256,256,0,stream>>>(solvent_x, sv16, NGRAPH, NGRAPH);
  gemm_f16<1,0><<<dim3(4,NBLK),256,0,stream>>>(xa16, 64, wx16, 64, xembB, h_f, 512, 64, nullptr, 1<<30);
  hipMemsetAsync(stats,0,(size_t)NLAYER*2*DIM*4,stream);

  // ---- edge CSR ----
  hipMemsetAsync(deg,0,degpad*2,stream);           // deg + cnt2
  hist_kernel<<<(NEDGES+255)/256,256,0,stream>>>(eidx+NEDGES, deg, NEDGES);
  {
    int nb=(NNODES+255)/256;
    block_sums<<<nb,256,0,stream>>>(deg, bdeg, NNODES);   // bdeg as scratch psum
    scan_partials<<<1,256,0,stream>>>(bdeg, nb);
    scan_write<<<nb,256,0,stream>>>(deg, bdeg, rowptr, NNODES);
  }
  scatter_edges<<<(NEDGES+255)/256,256,0,stream>>>(eidx, eattr, rowptr, cnt2, es_pk);

  // ---- batch CSR ----
  hipMemsetAsync(bdeg,0,16384,stream);             // bdeg + bcnt
  hist_kernel<<<(NNODES+255)/256,256,0,stream>>>(batch, bdeg, NNODES);
  scan2048<<<1,1024,0,stream>>>(bdeg, browptr, NGRAPH);
  scatter_batch<<<(NNODES+255)/256,256,0,stream>>>(batch, browptr, bcnt, bnodes);

  // ---- GNN layers ----
  for(int l=0;l<NLAYER;++l){
    const float* e1=ee1+(size_t)l*6*DIM;
    const float* e2=ee2+(size_t)l*3*DIM;
    float* st=stats+(size_t)l*2*DIM;
    for(int b0=0;b0<NBLK;b0+=chb){
      int nb=NBLK-b0; if(nb>chb) nb=chb;
      int n0=b0*128, rows=nb*128;
      agg_kernel<<<2048,256,0,stream>>>(h_f, rowptr, es_pk, e1, e2, agg_c, n0, n0+rows);
      gemm_f16<1,0><<<dim3(8,nb),256,0,stream>>>(agg_c, 512, W1t+(size_t)l*1024*512, 512,
          m1b+(size_t)l*1024, t_c, 1024, 512, nullptr, 1<<30);
      gemm_f16<0,1><<<dim3(4,nb),256,0,stream>>>(t_c, 1024, W2t+(size_t)l*512*1024, 1024,
          m2b+(size_t)l*512, h2_f+(size_t)n0*DIM, 512, 1024, st, NNODES-n0);
    }
    if(l<NLAYER-1)
      bn_apply<<<2048,256,0,stream>>>(h2_f, st, gam+(size_t)l*DIM, bet+(size_t)l*DIM, h_f);
  }

  // ---- pooling (layer-4 BN fused) + solvent + readout ----
  batch_reduce<<<512,256,0,stream>>>(h2_f, stats+(size_t)(NLAYER-1)*2*DIM,
      gam+(size_t)(NLAYER-1)*DIM, bet+(size_t)(NLAYER-1)*DIM, browptr, bnodes, z);
  gemm_f16<1,0><<<dim3(4,16),256,0,stream>>>(sv16, 64, ws1t, 64, sb1, s1, 512, 64, nullptr, 1<<30);
  gemm_f16<0,0><<<dim3(4,16),256,0,stream>>>(s1, 512, sW2t, 512, sb2, z+512, 1024, 512, nullptr, 1<<30);
  gemm_f16<1,0><<<dim3(4,16),256,0,stream>>>(z, 1024, oW0t, 1024, ob0, z0, 512, 1024, nullptr, 1<<30);
  gemm_f16<1,0><<<dim3(2,16),256,0,stream>>>(z0, 512, oW1t, 512, ob1, z1, 256, 512, nullptr, 1<<30);
  gemm_f16<1,0><<<dim3(1,16),256,0,stream>>>(z1, 256, oW2t, 256, ob2, z2, 128, 256, nullptr, 1<<30);
  last_kernel<<<NGRAPH/4,256,0,stream>>>(z2, lW, lb, out);
}